// Round 13
// baseline (826.630 us; speedup 1.0000x reference)
//
#include <hip/hip_runtime.h>
#include <hip/hip_bf16.h>
#include <stdint.h>

#define T_TOK 4096
#define HDIM  2048
#define IDIM  1408
#define NEXP  8
#define SIDIM 2816
#define GU_CAP 781   // 39*11 + 352
#define DN_CAP 568   // 39*8 + 256 (uniform NKT=22 tiles)

typedef __bf16 bf16_t;
typedef __bf16 bf16x8 __attribute__((ext_vector_type(8)));
typedef __bf16 bf16x4 __attribute__((ext_vector_type(4)));
typedef float  f32x4  __attribute__((ext_vector_type(4)));

typedef uint32_t __attribute__((address_space(3))) lds_u32;
typedef uint32_t __attribute__((address_space(1))) glb_u32;

__device__ __forceinline__ void glds16(const bf16_t* g, const char* l) {
  __builtin_amdgcn_global_load_lds((const glb_u32*)g, (lds_u32*)l, 16, 0, 0);
}

__device__ __forceinline__ void bar() {
  asm volatile("" ::: "memory");
  __builtin_amdgcn_s_barrier();
  asm volatile("" ::: "memory");
}
#define VMW4 asm volatile("s_waitcnt vmcnt(4)" ::: "memory")
#define VMW0 asm volatile("s_waitcnt vmcnt(0)" ::: "memory")

// m204 bijective XCD swizzle
__device__ __forceinline__ int xcd_swz(int orig, int nwg) {
  int q = nwg >> 3, r = nwg & 7;
  int x = orig & 7, i = orig >> 3;
  return (x < r ? x * (q + 1) : r * (q + 1) + (x - r) * q) + i;
}

// ---------------- merged transpose+convert: ALL weights in ONE dispatch ----------------
__global__ void tcvt_all_kernel(const float* __restrict__ gate, const float* __restrict__ up,
                                const float* __restrict__ sgw, const float* __restrict__ suw,
                                const float* __restrict__ down, const float* __restrict__ sdw,
                                bf16_t* __restrict__ BguR, bf16_t* __restrict__ BguS,
                                bf16_t* __restrict__ dT, bf16_t* __restrict__ sdT) {
  const int b = blockIdx.x;
  const float* in; bf16_t* out; int R, C, bx, by, which = 0; bool gu;
  if (b < 11264) {                        // gu-routed: 16 z x 22 x x 32 y
    int z = b / 704, rem = b - z * 704;
    bx = rem % 22; by = rem / 22;
    int e = z >> 1; which = z & 1;
    in = (which ? up : gate) + (size_t)e * HDIM * IDIM;
    out = BguR + (size_t)e * (2 * IDIM) * HDIM;
    R = HDIM; C = IDIM; gu = true;
  } else if (b < 14080) {                 // gu-shared: 2 z x 44 x x 32 y
    int k = b - 11264;
    int z = k / 1408, rem = k - z * 1408;
    bx = rem % 44; by = rem / 44;
    which = z;
    in = which ? suw : sgw;
    out = BguS;
    R = HDIM; C = SIDIM; gu = true;
  } else if (b < 19712) {                 // dT: 8 z x 32 x x 22 y
    int k = b - 14080;
    int z = k / 704, rem = k - z * 704;
    bx = rem % 32; by = rem / 32;
    in = down + (size_t)z * IDIM * HDIM;
    out = dT + (size_t)z * HDIM * IDIM;
    R = IDIM; C = HDIM; gu = false;
  } else {                                // sdT: 32 x x 44 y
    int k = b - 19712;
    bx = k % 32; by = k / 32;
    in = sdw; out = sdT;
    R = SIDIM; C = HDIM; gu = false;
  }
  __shared__ float tf[64 * 64];
  const int r0 = by * 64, c0 = bx * 64;
  const int tid = threadIdx.x;
  const int cb = tid & 15, rr = tid >> 4;
#pragma unroll
  for (int s = 0; s < 4; ++s) {
    int r = rr + 16 * s;
    float4 v = *(const float4*)(in + (size_t)(r0 + r) * C + c0 + cb * 4);
    int slot = (cb ^ (r & 7) ^ ((r >> 4) << 1)) & 15;
    *(float4*)&tf[r * 64 + slot * 4] = v;
  }
  __syncthreads();
  const int c = tid >> 2, rb = (tid & 3) * 16;
  bf16x8 w0, w1;
#pragma unroll
  for (int i = 0; i < 16; ++i) {
    int r = rb + i;
    int slot = ((c >> 2) ^ (r & 7) ^ ((r >> 4) << 1)) & 15;
    float v = tf[r * 64 + slot * 4 + (c & 3)];
    if (i < 8) w0[i] = (bf16_t)v; else w1[i - 8] = (bf16_t)v;
  }
  int cg = c0 + c;
  int nprime = gu ? (((cg >> 4) << 5) + which * 16 + (cg & 15)) : cg;
  bf16_t* op = out + (size_t)nprime * R + r0 + rb;
  *(bf16x8*)op = w0;
  *(bf16x8*)(op + 8) = w1;
}

// ---------------- router (fused x f32->bf16 conversion) ----------------
__global__ void router_kernel(const float* __restrict__ x, const float* __restrict__ rw,
                              bf16_t* __restrict__ xb,
                              int* __restrict__ tk_i, float* __restrict__ tk_w,
                              int* __restrict__ counts) {
  int gtid = blockIdx.x * 256 + threadIdx.x;
  int t = gtid >> 6, lane = gtid & 63;
  const float4* xr = (const float4*)(x + (size_t)t * HDIM);
  bf16x4* xo = (bf16x4*)(xb + (size_t)t * HDIM);
  float acc[NEXP];
#pragma unroll
  for (int e = 0; e < NEXP; e++) acc[e] = 0.f;
  for (int i = lane; i < HDIM / 4; i += 64) {
    float4 xv = xr[i];
    bf16x4 o;
    o[0] = (bf16_t)xv.x; o[1] = (bf16_t)xv.y; o[2] = (bf16_t)xv.z; o[3] = (bf16_t)xv.w;
    xo[i] = o;
#pragma unroll
    for (int e = 0; e < NEXP; e++) {
      float4 wv = ((const float4*)(rw + e * HDIM))[i];
      acc[e] += xv.x * wv.x + xv.y * wv.y + xv.z * wv.z + xv.w * wv.w;
    }
  }
#pragma unroll
  for (int e = 0; e < NEXP; e++)
#pragma unroll
    for (int off = 32; off; off >>= 1) acc[e] += __shfl_down(acc[e], off);
  if (lane == 0) {
    int i1 = 0; float m1 = acc[0];
#pragma unroll
    for (int e = 1; e < NEXP; e++) if (acc[e] > m1) { m1 = acc[e]; i1 = e; }
    int i2 = -1; float m2 = -1e30f;
#pragma unroll
    for (int e = 0; e < NEXP; e++) if (e != i1 && acc[e] > m2) { m2 = acc[e]; i2 = e; }
    float w1 = 1.f / (1.f + __expf(m2 - m1));
    tk_i[t * 2] = i1; tk_i[t * 2 + 1] = i2;
    tk_w[t * 2] = w1; tk_w[t * 2 + 1] = 1.f - w1;
    atomicAdd(&counts[i1], 1); atomicAdd(&counts[i2], 1);
  }
}

// ---------------- scatter: self-computed prefix ----------------
__global__ void scatter_kernel(const int* __restrict__ tk_i,
                               int* __restrict__ meta, int* __restrict__ tok_idx,
                               int* __restrict__ tk_slot) {
  __shared__ int offs[NEXP];
  if (threadIdx.x < NEXP) {
    int o = 0;
    for (int i = 0; i < (int)threadIdx.x; ++i) o += meta[i];
    offs[threadIdx.x] = o;
  }
  __syncthreads();
  int t = blockIdx.x * 256 + threadIdx.x;
  if (t >= T_TOK) return;
#pragma unroll
  for (int k = 0; k < 2; k++) {
    int e = tk_i[t * 2 + k];
    int pos = offs[e] + atomicAdd(&meta[8 + e], 1);
    tok_idx[pos] = t; tk_slot[t * 2 + k] = pos;
  }
}

// ---------------- fused 8-phase 256x256 GEMM, quadrant-pipelined ----------------
// Every MMQ consumes fragments read >=1 phase earlier; each phase's new ds_reads
// have no consumer in-phase -> MFMA issues immediately post-barrier while reads
// flow down the LDS pipe. vmcnt FIFO identical to the proven round-5 schedule.
template <int OP>
__device__ __forceinline__
void gemm8p_body(const bf16_t* __restrict__ A0, const bf16_t* __restrict__ A1,
                 const bf16_t* __restrict__ B0, const bf16_t* __restrict__ B1,
                 bf16_t* __restrict__ O0, bf16_t* __restrict__ O1, bf16_t* __restrict__ O2,
                 const float* __restrict__ bg, const float* __restrict__ bu,
                 const int* __restrict__ meta, const int* __restrict__ tok_idx) {
  // per-expert tile counts + prefix from counts[8]
  int nt[NEXP], offp[NEXP];
  int nmt = 0, osum = 0;
#pragma unroll
  for (int i = 0; i < NEXP; ++i) {
    offp[i] = osum; osum += meta[i];
    nt[i] = (meta[i] + 255) >> 8;
    nmt += nt[i];
  }
  const int ntiles = (OP == 0) ? (nmt * 11 + 352) : (nmt * 8 + 256);
  const int l = blockIdx.x;
  if (l >= ntiles) return;
  const int s = xcd_swz(l, ntiles);

  int kind, e = 0, row0, n0, ks = 0;
  if (OP == 0) {
    if (s < nmt * 11) {
      kind = 0;
      int g = s / (nmt * 2), rem = s - g * (nmt * 2);
      int yt, xt;
      if (g < 5) { yt = rem >> 1; xt = g * 2 + (rem & 1); }
      else       { yt = rem;      xt = 10; }
      int acc = 0, ytin = 0;
#pragma unroll
      for (int i = 0; i < NEXP; ++i) { if (yt >= acc) { e = i; ytin = yt - acc; } acc += nt[i]; }
      row0 = ytin << 8; n0 = xt * 256;
    } else {
      kind = 1;
      int k = s - nmt * 11, g = k >> 5, rem = k & 31;
      row0 = (rem >> 1) * 256; n0 = (g * 2 + (rem & 1)) * 256;
    }
  } else {
    if (s < nmt * 8) {
      kind = 0;
      int g = s / (nmt * 2), rem = s - g * (nmt * 2);
      int yt = rem >> 1, xt = g * 2 + (rem & 1);
      int acc = 0, ytin = 0;
#pragma unroll
      for (int i = 0; i < NEXP; ++i) { if (yt >= acc) { e = i; ytin = yt - acc; } acc += nt[i]; }
      row0 = ytin << 8; n0 = xt * 256;
    } else {
      kind = 1;
      int k = s - nmt * 8;
      int xt = k >> 5, rem = k & 31;
      ks = rem >> 4;
      row0 = (rem & 15) * 256; n0 = xt * 256;
    }
  }

  int cnt, slot0 = 0, strideA, strideB, koff = 0;
  const bf16_t *Ab, *Bp;
  constexpr int NKT = (OP == 0) ? (HDIM / 64) : (IDIM / 64);  // 32 | 22
  if (OP == 0) {
    strideA = HDIM; strideB = HDIM; Ab = A0;
    if (kind == 0) {
      slot0 = offp[e]; cnt = meta[e];
      Bp = B0 + (size_t)e * (2 * IDIM) * HDIM;
    } else { cnt = T_TOK; Bp = B1; }
  } else {
    if (kind == 0) {
      slot0 = offp[e]; cnt = meta[e];
      Ab = A0; strideA = IDIM;
      Bp = B0 + (size_t)e * HDIM * IDIM; strideB = IDIM;
    } else {
      cnt = T_TOK; Ab = A1; strideA = SIDIM;
      Bp = B1; strideB = SIDIM; koff = ks * IDIM;
    }
  }

  __shared__ __align__(16) char smem[131072];

  const int t = threadIdx.x;
  const int lane = t & 63, wid = t >> 6;
  const int wr = wid >> 2, wc = wid & 3;
  const int lr = lane & 15, lg = lane >> 4;

  const bf16_t* pA[4]; const bf16_t* pB[4]; int dG[4];
#pragma unroll
  for (int j = 0; j < 4; ++j) {
    int g = j * 512 + t;
    int r = g >> 3;
    int c16 = (g & 7) ^ (r & 7);
    dG[j] = g * 16;
    int rr = row0 + r;
    if (kind == 0 && rr >= cnt) rr = cnt - 1;
    int arow;
    if (OP == 0 && kind == 0) arow = tok_idx[slot0 + rr];
    else if (OP == 1 && kind == 0) arow = slot0 + rr;
    else arow = rr;
    pA[j] = Ab + (size_t)arow * strideA + koff + c16 * 8;
    pB[j] = Bp + (size_t)(n0 + r) * strideB + koff + c16 * 8;
  }

  const int cswz0 = ((lg) ^ (lr & 7)) * 16;
  const int cswz1 = ((4 + lg) ^ (lr & 7)) * 16;
  const int aRowB = (wr * 128 + lr) * 128;
  const int bRowB = (wc * 64 + lr) * 128 + 65536;

  f32x4 acc[8][4];
#pragma unroll
  for (int mi = 0; mi < 8; ++mi)
#pragma unroll
    for (int ni = 0; ni < 4; ++ni) acc[mi][ni] = (f32x4)(0.f);

  bf16x8 aL[4][2], aH[4][2], bL[2][2], bH[2][2];

#define ST_A(BUFO, KT, JH) { \
    glds16(pA[(JH)*2]   + (KT)*64, smem + (BUFO) + dG[(JH)*2]); \
    glds16(pA[(JH)*2+1] + (KT)*64, smem + (BUFO) + dG[(JH)*2+1]); }
#define ST_B(BUFO, KT, JH) { \
    glds16(pB[(JH)*2]   + (KT)*64, smem + 65536 + (BUFO) + dG[(JH)*2]); \
    glds16(pB[(JH)*2+1] + (KT)*64, smem + 65536 + (BUFO) + dG[(JH)*2+1]); }
#define RD_A(af, BUFO, MIH) { \
    _Pragma("unroll") for (int mi = 0; mi < 4; ++mi) { \
      af[mi][0] = *(const bf16x8*)(smem + (BUFO) + aRowB + (MIH)*8192 + mi*2048 + cswz0); \
      af[mi][1] = *(const bf16x8*)(smem + (BUFO) + aRowB + (MIH)*8192 + mi*2048 + cswz1); } }
#define RD_B(bf, BUFO, NIH) { \
    _Pragma("unroll") for (int ni = 0; ni < 2; ++ni) { \
      bf[ni][0] = *(const bf16x8*)(smem + (BUFO) + bRowB + (NIH)*4096 + ni*2048 + cswz0); \
      bf[ni][1] = *(const bf16x8*)(smem + (BUFO) + bRowB + (NIH)*4096 + ni*2048 + cswz1); } }
#define MMQ(af, bf, MO, NO) { \
    __builtin_amdgcn_s_setprio(1); \
    _Pragma("unroll") for (int ni = 0; ni < 2; ++ni) \
    _Pragma("unroll") for (int mi = 0; mi < 4; ++mi) { \
      acc[(MO)+mi][(NO)+ni] = __builtin_amdgcn_mfma_f32_16x16x32_bf16(af[mi][0], bf[ni][0], acc[(MO)+mi][(NO)+ni], 0, 0, 0); \
      acc[(MO)+mi][(NO)+ni] = __builtin_amdgcn_mfma_f32_16x16x32_bf16(af[mi][1], bf[ni][1], acc[(MO)+mi][(NO)+ni], 0, 0, 0); } \
    __builtin_amdgcn_s_setprio(0); }
// Quadrant-pipelined KTILE: MMQ operands were read >=1 phase earlier.
//   P1: RD aH(cur)  + MMQ(aL,bL)    P2: RD bH(cur) + MMQ(aH,bL)
//   P3:               MMQ(aL,bH)    P4: VMW; RD aL,bL(next buf) + MMQ(aH,bH)
// Liveness: aL used P1,P3 (re-read P4); bL used P1,P2 (re-read P4);
//           aH read P1, used P2,P4; bH read P2, used P3,P4. No clobbers.
#define KTILE(KT, BO, NBO, W) { \
    if ((KT) + 1 < NKT) ST_B(NBO, (KT) + 1, 0); \
    bar(); RD_A(aH, BO, 1); MMQ(aL, bL, 0, 0); bar(); \
    if ((KT) + 1 < NKT) ST_B(NBO, (KT) + 1, 1); \
    bar(); RD_B(bH, BO, 1); MMQ(aH, bL, 4, 0); bar(); \
    if ((KT) + 2 < NKT) ST_A(BO, (KT) + 2, 0); \
    bar(); MMQ(aL, bH, 0, 2); bar(); \
    if ((KT) + 2 < NKT) ST_A(BO, (KT) + 2, 1); \
    W; bar(); \
    if ((KT) + 1 < NKT) { RD_A(aL, NBO, 0); RD_B(bL, NBO, 0); } \
    MMQ(aH, bH, 4, 2); bar(); }

  // prologue: stage t0 (A+B) and A(t1); wait (leaves A(t1) flying); preload Q1 frags
  ST_A(0, 0, 0); ST_A(0, 0, 1);
  ST_B(0, 0, 0); ST_B(0, 0, 1);
  ST_A(32768, 1, 0); ST_A(32768, 1, 1);
  VMW4; bar();
  RD_A(aL, 0, 0); RD_B(bL, 0, 0);

  // steady-state vmcnt(4); tail: last two tiles drain fully (fewer stages issued)
  for (int kt = 0; kt < NKT - 2; kt += 2) {
    KTILE(kt, 0, 32768, VMW4);
    KTILE(kt + 1, 32768, 0, VMW4);
  }
  KTILE(NKT - 2, 0, 32768, VMW0);
  KTILE(NKT - 1, 32768, 0, VMW0);

  if (OP == 0) {
    // in-register SwiGLU: gate in acc[.][even], up in acc[.][odd] (16-col interleave)
    bf16_t* Ho = kind ? O1 : O0;
    const int HN = kind ? SIDIM : IDIM;
    const int Lbase = n0 >> 1;
#pragma unroll
    for (int mi = 0; mi < 8; ++mi)
#pragma unroll
      for (int j = 0; j < 4; ++j) {
        int row = wr * 128 + mi * 16 + lg * 4 + j;
        int grow = row0 + row;
        if (kind == 0 && grow >= cnt) continue;
        size_t orow = (size_t)((kind ? 0 : slot0) + grow);
#pragma unroll
        for (int nih = 0; nih < 2; ++nih) {
          int Lr = wc * 32 + nih * 16 + lr;
          float g = acc[mi][2 * nih][j];
          float u = acc[mi][2 * nih + 1][j];
          if (kind) { g += bg[Lbase + Lr]; u += bu[Lbase + Lr]; }
          float h = (g / (1.f + __expf(-g))) * u;
          Ho[orow * HN + Lbase + Lr] = (bf16_t)h;
        }
      }
  } else {
    bf16_t* Po = kind ? (ks ? O2 : O1) : O0;
#pragma unroll
    for (int mi = 0; mi < 8; ++mi)
#pragma unroll
      for (int j = 0; j < 4; ++j) {
        int row = wr * 128 + mi * 16 + lg * 4 + j;
        int grow = row0 + row;
        if (kind == 0 && grow >= cnt) continue;
        size_t orow = (size_t)((kind ? 0 : slot0) + grow);
#pragma unroll
        for (int ni = 0; ni < 4; ++ni) {
          int col = n0 + wc * 64 + ni * 16 + lr;
          Po[orow * HDIM + col] = (bf16_t)acc[mi][ni][j];
        }
      }
  }
#undef ST_A
#undef ST_B
#undef RD_A
#undef RD_B
#undef MMQ
#undef KTILE
}

__global__ __launch_bounds__(512, 2)
void gu_gemm(const bf16_t* A0, const bf16_t* A1, const bf16_t* B0, const bf16_t* B1,
             bf16_t* O0, bf16_t* O1, bf16_t* O2, const float* bg, const float* bu,
             const int* meta, const int* tok_idx) {
  gemm8p_body<0>(A0, A1, B0, B1, O0, O1, O2, bg, bu, meta, tok_idx);
}
__global__ __launch_bounds__(512, 2)
void dn_gemm(const bf16_t* A0, const bf16_t* A1, const bf16_t* B0, const bf16_t* B1,
             bf16_t* O0, bf16_t* O1, bf16_t* O2, const float* bg, const float* bu,
             const int* meta, const int* tok_idx) {
  gemm8p_body<1>(A0, A1, B0, B1, O0, O1, O2, bg, bu, meta, tok_idx);
}

// out[t] = sh0[t]+sh1[t] + w1*rt[s1] + w2*rt[s2] + sdb
__global__ void combine_kernel(const bf16_t* __restrict__ sh0, const bf16_t* __restrict__ sh1,
                               const bf16_t* __restrict__ rt, const int* __restrict__ tk_slot,
                               const float* __restrict__ tk_w, const float* __restrict__ sdb,
                               float* __restrict__ out) {
  const int t = blockIdx.x;
  const int c = threadIdx.x * 8;
  const int s1 = tk_slot[2 * t], s2 = tk_slot[2 * t + 1];
  const float w1 = tk_w[2 * t], w2 = tk_w[2 * t + 1];
  bf16x8 a = *(const bf16x8*)(sh0 + (size_t)t * HDIM + c);
  bf16x8 b = *(const bf16x8*)(sh1 + (size_t)t * HDIM + c);
  bf16x8 r1 = *(const bf16x8*)(rt + (size_t)s1 * HDIM + c);
  bf16x8 r2 = *(const bf16x8*)(rt + (size_t)s2 * HDIM + c);
  float4 d0 = *(const float4*)(sdb + c);
  float4 d1 = *(const float4*)(sdb + c + 4);
  float o[8];
#pragma unroll
  for (int i = 0; i < 8; i++)
    o[i] = (float)a[i] + (float)b[i] + w1 * (float)r1[i] + w2 * (float)r2[i];
  o[0] += d0.x; o[1] += d0.y; o[2] += d0.z; o[3] += d0.w;
  o[4] += d1.x; o[5] += d1.y; o[6] += d1.z; o[7] += d1.w;
  float4* op = (float4*)(out + (size_t)t * HDIM + c);
  op[0] = make_float4(o[0], o[1], o[2], o[3]);
  op[1] = make_float4(o[4], o[5], o[6], o[7]);
}

extern "C" void kernel_launch(void* const* d_in, const int* in_sizes, int n_in,
                              void* d_out, int out_size, void* d_ws, size_t ws_size,
                              hipStream_t stream) {
  const float* x_f  = (const float*)d_in[0];
  const float* rw   = (const float*)d_in[1];
  const float* gate = (const float*)d_in[2];
  const float* up   = (const float*)d_in[3];
  const float* down = (const float*)d_in[4];
  const float* sgw  = (const float*)d_in[5];
  const float* sgb  = (const float*)d_in[6];
  const float* suw  = (const float*)d_in[7];
  const float* sub  = (const float*)d_in[8];
  const float* sdw  = (const float*)d_in[9];
  const float* sdb  = (const float*)d_in[10];
  float* out = (float*)d_out;

  char* ws = (char*)d_ws;
  size_t off = 0;
  auto alloc = [&](size_t bytes) {
    char* p = ws + off;
    off += (bytes + 255) & ~(size_t)255;
    return p;
  };
  bf16_t* xb    = (bf16_t*)alloc((size_t)T_TOK * HDIM * 2);
  char*   bgur  = alloc((size_t)NEXP * 2 * IDIM * HDIM * 2);            // 92.3MB
  bf16_t* BguR  = (bf16_t*)bgur;
  bf16_t* BguS  = (bf16_t*)alloc((size_t)2 * SIDIM * HDIM * 2);
  bf16_t* dT    = (bf16_t*)alloc((size_t)NEXP * HDIM * IDIM * 2);
  bf16_t* sdT   = (bf16_t*)alloc((size_t)HDIM * SIDIM * 2);
  bf16_t* hid_r = (bf16_t*)alloc((size_t)(T_TOK * 2) * IDIM * 2);
  bf16_t* hid_s = (bf16_t*)alloc((size_t)T_TOK * SIDIM * 2);
  int*    meta  = (int*)alloc(1024);
  int*    tok_idx = (int*)alloc(8192 * 4);
  int*    tk_slot = (int*)alloc(8192 * 4);
  int*    tk_i    = (int*)alloc((size_t)T_TOK * 2 * 4);
  float*  tk_w2   = (float*)alloc((size_t)T_TOK * 2 * 4);

  // down partials alias BguR (dead after gateup dispatch): 33.6+16.8+16.8 <= 92.3MB
  bf16_t* rt_p  = (bf16_t*)bgur;
  bf16_t* sh_p0 = (bf16_t*)(bgur + (size_t)8192 * HDIM * 2);
  bf16_t* sh_p1 = (bf16_t*)(bgur + (size_t)8192 * HDIM * 2 + (size_t)T_TOK * HDIM * 2);

  hipMemsetAsync(meta, 0, 64, stream);  // counts + cursor

  tcvt_all_kernel<<<21120, 256, 0, stream>>>(
      gate, up, sgw, suw, down, sdw, BguR, BguS, dT, sdT);

  router_kernel<<<T_TOK / 4, 256, 0, stream>>>(x_f, rw, xb, tk_i, tk_w2, meta);
  scatter_kernel<<<T_TOK / 256, 256, 0, stream>>>(tk_i, meta, tok_idx, tk_slot);

  gu_gemm<<<GU_CAP, 512, 0, stream>>>(
      xb, nullptr, BguR, BguS, hid_r, hid_s, nullptr, sgb, sub, meta, tok_idx);
  dn_gemm<<<DN_CAP, 512, 0, stream>>>(
      hid_r, hid_s, dT, sdT, rt_p, sh_p0, sh_p1, nullptr, nullptr, meta, nullptr);
  combine_kernel<<<T_TOK, 256, 0, stream>>>(sh_p0, sh_p1, rt_p, tk_slot, tk_w2, sdb, out);
}

// Round 14
// 568.769 us; speedup vs baseline: 1.4534x; 1.4534x over previous
//
#include <hip/hip_runtime.h>
#include <hip/hip_bf16.h>
#include <stdint.h>

#define T_TOK 4096
#define HDIM  2048
#define IDIM  1408
#define NEXP  8
#define SIDIM 2816
#define GU_CAP 781   // 39*11 + 352
#define DN_CAP 568   // 39*8 + 256 (uniform NKT=22 tiles)

typedef __bf16 bf16_t;
typedef __bf16 bf16x8 __attribute__((ext_vector_type(8)));
typedef __bf16 bf16x4 __attribute__((ext_vector_type(4)));
typedef float  f32x4  __attribute__((ext_vector_type(4)));

typedef uint32_t __attribute__((address_space(3))) lds_u32;
typedef uint32_t __attribute__((address_space(1))) glb_u32;

__device__ __forceinline__ void glds16(const bf16_t* g, const char* l) {
  __builtin_amdgcn_global_load_lds((const glb_u32*)g, (lds_u32*)l, 16, 0, 0);
}

__device__ __forceinline__ void bar() {
  asm volatile("" ::: "memory");
  __builtin_amdgcn_s_barrier();
  asm volatile("" ::: "memory");
}
#define VMW4 asm volatile("s_waitcnt vmcnt(4)" ::: "memory")
#define VMW0 asm volatile("s_waitcnt vmcnt(0)" ::: "memory")
// template line: partial LDS drain before the barrier when 12 ds_reads in flight
#define LGK8 asm volatile("s_waitcnt lgkmcnt(8)" ::: "memory")

// m204 bijective XCD swizzle
__device__ __forceinline__ int xcd_swz(int orig, int nwg) {
  int q = nwg >> 3, r = nwg & 7;
  int x = orig & 7, i = orig >> 3;
  return (x < r ? x * (q + 1) : r * (q + 1) + (x - r) * q) + i;
}

// ---------------- merged transpose+convert: ALL weights in ONE dispatch ----------------
__global__ void tcvt_all_kernel(const float* __restrict__ gate, const float* __restrict__ up,
                                const float* __restrict__ sgw, const float* __restrict__ suw,
                                const float* __restrict__ down, const float* __restrict__ sdw,
                                bf16_t* __restrict__ BguR, bf16_t* __restrict__ BguS,
                                bf16_t* __restrict__ dT, bf16_t* __restrict__ sdT) {
  const int b = blockIdx.x;
  const float* in; bf16_t* out; int R, C, bx, by, which = 0; bool gu;
  if (b < 11264) {                        // gu-routed: 16 z x 22 x x 32 y
    int z = b / 704, rem = b - z * 704;
    bx = rem % 22; by = rem / 22;
    int e = z >> 1; which = z & 1;
    in = (which ? up : gate) + (size_t)e * HDIM * IDIM;
    out = BguR + (size_t)e * (2 * IDIM) * HDIM;
    R = HDIM; C = IDIM; gu = true;
  } else if (b < 14080) {                 // gu-shared: 2 z x 44 x x 32 y
    int k = b - 11264;
    int z = k / 1408, rem = k - z * 1408;
    bx = rem % 44; by = rem / 44;
    which = z;
    in = which ? suw : sgw;
    out = BguS;
    R = HDIM; C = SIDIM; gu = true;
  } else if (b < 19712) {                 // dT: 8 z x 32 x x 22 y
    int k = b - 14080;
    int z = k / 704, rem = k - z * 704;
    bx = rem % 32; by = rem / 32;
    in = down + (size_t)z * IDIM * HDIM;
    out = dT + (size_t)z * HDIM * IDIM;
    R = IDIM; C = HDIM; gu = false;
  } else {                                // sdT: 32 x x 44 y
    int k = b - 19712;
    bx = k % 32; by = k / 32;
    in = sdw; out = sdT;
    R = SIDIM; C = HDIM; gu = false;
  }
  __shared__ float tf[64 * 64];
  const int r0 = by * 64, c0 = bx * 64;
  const int tid = threadIdx.x;
  const int cb = tid & 15, rr = tid >> 4;
#pragma unroll
  for (int s = 0; s < 4; ++s) {
    int r = rr + 16 * s;
    float4 v = *(const float4*)(in + (size_t)(r0 + r) * C + c0 + cb * 4);
    int slot = (cb ^ (r & 7) ^ ((r >> 4) << 1)) & 15;
    *(float4*)&tf[r * 64 + slot * 4] = v;
  }
  __syncthreads();
  const int c = tid >> 2, rb = (tid & 3) * 16;
  bf16x8 w0, w1;
#pragma unroll
  for (int i = 0; i < 16; ++i) {
    int r = rb + i;
    int slot = ((c >> 2) ^ (r & 7) ^ ((r >> 4) << 1)) & 15;
    float v = tf[r * 64 + slot * 4 + (c & 3)];
    if (i < 8) w0[i] = (bf16_t)v; else w1[i - 8] = (bf16_t)v;
  }
  int cg = c0 + c;
  int nprime = gu ? (((cg >> 4) << 5) + which * 16 + (cg & 15)) : cg;
  bf16_t* op = out + (size_t)nprime * R + r0 + rb;
  *(bf16x8*)op = w0;
  *(bf16x8*)(op + 8) = w1;
}

// ---------------- router (fused x f32->bf16 conversion) ----------------
__global__ void router_kernel(const float* __restrict__ x, const float* __restrict__ rw,
                              bf16_t* __restrict__ xb,
                              int* __restrict__ tk_i, float* __restrict__ tk_w,
                              int* __restrict__ counts) {
  int gtid = blockIdx.x * 256 + threadIdx.x;
  int t = gtid >> 6, lane = gtid & 63;
  const float4* xr = (const float4*)(x + (size_t)t * HDIM);
  bf16x4* xo = (bf16x4*)(xb + (size_t)t * HDIM);
  float acc[NEXP];
#pragma unroll
  for (int e = 0; e < NEXP; e++) acc[e] = 0.f;
  for (int i = lane; i < HDIM / 4; i += 64) {
    float4 xv = xr[i];
    bf16x4 o;
    o[0] = (bf16_t)xv.x; o[1] = (bf16_t)xv.y; o[2] = (bf16_t)xv.z; o[3] = (bf16_t)xv.w;
    xo[i] = o;
#pragma unroll
    for (int e = 0; e < NEXP; e++) {
      float4 wv = ((const float4*)(rw + e * HDIM))[i];
      acc[e] += xv.x * wv.x + xv.y * wv.y + xv.z * wv.z + xv.w * wv.w;
    }
  }
#pragma unroll
  for (int e = 0; e < NEXP; e++)
#pragma unroll
    for (int off = 32; off; off >>= 1) acc[e] += __shfl_down(acc[e], off);
  if (lane == 0) {
    int i1 = 0; float m1 = acc[0];
#pragma unroll
    for (int e = 1; e < NEXP; e++) if (acc[e] > m1) { m1 = acc[e]; i1 = e; }
    int i2 = -1; float m2 = -1e30f;
#pragma unroll
    for (int e = 0; e < NEXP; e++) if (e != i1 && acc[e] > m2) { m2 = acc[e]; i2 = e; }
    float w1 = 1.f / (1.f + __expf(m2 - m1));
    tk_i[t * 2] = i1; tk_i[t * 2 + 1] = i2;
    tk_w[t * 2] = w1; tk_w[t * 2 + 1] = 1.f - w1;
    atomicAdd(&counts[i1], 1); atomicAdd(&counts[i2], 1);
  }
}

// ---------------- scatter: self-computed prefix (no build kernel) ----------------
// meta: [0..7] counts (router), [8..15] cursor
__global__ void scatter_kernel(const int* __restrict__ tk_i,
                               int* __restrict__ meta, int* __restrict__ tok_idx,
                               int* __restrict__ tk_slot) {
  __shared__ int offs[NEXP];
  if (threadIdx.x < NEXP) {
    int o = 0;
    for (int i = 0; i < (int)threadIdx.x; ++i) o += meta[i];
    offs[threadIdx.x] = o;
  }
  __syncthreads();
  int t = blockIdx.x * 256 + threadIdx.x;
  if (t >= T_TOK) return;
#pragma unroll
  for (int k = 0; k < 2; k++) {
    int e = tk_i[t * 2 + k];
    int pos = offs[e] + atomicAdd(&meta[8 + e], 1);
    tok_idx[pos] = t; tk_slot[t * 2 + k] = pos;
  }
}

// ---------------- fused 8-phase 256x256 GEMM, SELF-DECODED tile table ----------------
// ROUND-5 schedule (proven): per phase {ds_read frags, stage, barrier, MMQ, barrier};
// counted vmcnt(4) steady-state, full drain on the peeled 2-tile tail.
template <int OP>
__device__ __forceinline__
void gemm8p_body(const bf16_t* __restrict__ A0, const bf16_t* __restrict__ A1,
                 const bf16_t* __restrict__ B0, const bf16_t* __restrict__ B1,
                 bf16_t* __restrict__ O0, bf16_t* __restrict__ O1, bf16_t* __restrict__ O2,
                 const float* __restrict__ bg, const float* __restrict__ bu,
                 const int* __restrict__ meta, const int* __restrict__ tok_idx) {
  // per-expert tile counts + prefix from counts[8]
  int nt[NEXP], offp[NEXP];
  int nmt = 0, osum = 0;
#pragma unroll
  for (int i = 0; i < NEXP; ++i) {
    offp[i] = osum; osum += meta[i];
    nt[i] = (meta[i] + 255) >> 8;
    nmt += nt[i];
  }
  const int ntiles = (OP == 0) ? (nmt * 11 + 352) : (nmt * 8 + 256);
  const int l = blockIdx.x;
  if (l >= ntiles) return;
  const int s = xcd_swz(l, ntiles);

  int kind, e = 0, row0, n0, ks = 0;
  if (OP == 0) {
    if (s < nmt * 11) {                      // routed, xt-paired (g<5), xt=10 singleton
      kind = 0;
      int g = s / (nmt * 2), rem = s - g * (nmt * 2);
      int yt, xt;
      if (g < 5) { yt = rem >> 1; xt = g * 2 + (rem & 1); }
      else       { yt = rem;      xt = 10; }
      int acc = 0, ytin = 0;
#pragma unroll
      for (int i = 0; i < NEXP; ++i) { if (yt >= acc) { e = i; ytin = yt - acc; } acc += nt[i]; }
      row0 = ytin << 8; n0 = xt * 256;
    } else {                                 // shared: 352 = 11 xt-pairs x 32
      kind = 1;
      int k = s - nmt * 11, g = k >> 5, rem = k & 31;
      row0 = (rem >> 1) * 256; n0 = (g * 2 + (rem & 1)) * 256;
    }
  } else {
    if (s < nmt * 8) {                       // routed, xt-paired
      kind = 0;
      int g = s / (nmt * 2), rem = s - g * (nmt * 2);
      int yt = rem >> 1, xt = g * 2 + (rem & 1);
      int acc = 0, ytin = 0;
#pragma unroll
      for (int i = 0; i < NEXP; ++i) { if (yt >= acc) { e = i; ytin = yt - acc; } acc += nt[i]; }
      row0 = ytin << 8; n0 = xt * 256;
    } else {                                 // shared: 256 = 8 xt x (2 ks x 16 yt)
      kind = 1;
      int k = s - nmt * 8;
      int xt = k >> 5, rem = k & 31;
      ks = rem >> 4;
      row0 = (rem & 15) * 256; n0 = xt * 256;
    }
  }

  int cnt, slot0 = 0, strideA, strideB, koff = 0;
  const bf16_t *Ab, *Bp;
  constexpr int NKT = (OP == 0) ? (HDIM / 64) : (IDIM / 64);  // 32 | 22
  if (OP == 0) {
    strideA = HDIM; strideB = HDIM; Ab = A0;
    if (kind == 0) {
      slot0 = offp[e]; cnt = meta[e];
      Bp = B0 + (size_t)e * (2 * IDIM) * HDIM;
    } else { cnt = T_TOK; Bp = B1; }
  } else {
    if (kind == 0) {
      slot0 = offp[e]; cnt = meta[e];
      Ab = A0; strideA = IDIM;
      Bp = B0 + (size_t)e * HDIM * IDIM; strideB = IDIM;
    } else {
      cnt = T_TOK; Ab = A1; strideA = SIDIM;
      Bp = B1; strideB = SIDIM; koff = ks * IDIM;
    }
  }

  __shared__ __align__(16) char smem[131072];

  const int t = threadIdx.x;
  const int lane = t & 63, wid = t >> 6;
  const int wr = wid >> 2, wc = wid & 3;
  const int lr = lane & 15, lg = lane >> 4;

  const bf16_t* pA[4]; const bf16_t* pB[4]; int dG[4];
#pragma unroll
  for (int j = 0; j < 4; ++j) {
    int g = j * 512 + t;
    int r = g >> 3;
    int c16 = (g & 7) ^ (r & 7);
    dG[j] = g * 16;
    int rr = row0 + r;
    if (kind == 0 && rr >= cnt) rr = cnt - 1;
    int arow;
    if (OP == 0 && kind == 0) arow = tok_idx[slot0 + rr];
    else if (OP == 1 && kind == 0) arow = slot0 + rr;
    else arow = rr;
    pA[j] = Ab + (size_t)arow * strideA + koff + c16 * 8;
    pB[j] = Bp + (size_t)(n0 + r) * strideB + koff + c16 * 8;
  }

  const int cswz0 = ((lg) ^ (lr & 7)) * 16;
  const int cswz1 = ((4 + lg) ^ (lr & 7)) * 16;
  const int aRowB = (wr * 128 + lr) * 128;
  const int bRowB = (wc * 64 + lr) * 128 + 65536;

  f32x4 acc[8][4];
#pragma unroll
  for (int mi = 0; mi < 8; ++mi)
#pragma unroll
    for (int ni = 0; ni < 4; ++ni) acc[mi][ni] = (f32x4)(0.f);

  bf16x8 aL[4][2], aH[4][2], bL[2][2], bH[2][2];

#define ST_A(BUFO, KT, JH) { \
    glds16(pA[(JH)*2]   + (KT)*64, smem + (BUFO) + dG[(JH)*2]); \
    glds16(pA[(JH)*2+1] + (KT)*64, smem + (BUFO) + dG[(JH)*2+1]); }
#define ST_B(BUFO, KT, JH) { \
    glds16(pB[(JH)*2]   + (KT)*64, smem + 65536 + (BUFO) + dG[(JH)*2]); \
    glds16(pB[(JH)*2+1] + (KT)*64, smem + 65536 + (BUFO) + dG[(JH)*2+1]); }
#define RD_A(af, BUFO, MIH) { \
    _Pragma("unroll") for (int mi = 0; mi < 4; ++mi) { \
      af[mi][0] = *(const bf16x8*)(smem + (BUFO) + aRowB + (MIH)*8192 + mi*2048 + cswz0); \
      af[mi][1] = *(const bf16x8*)(smem + (BUFO) + aRowB + (MIH)*8192 + mi*2048 + cswz1); } }
#define RD_B(bf, BUFO, NIH) { \
    _Pragma("unroll") for (int ni = 0; ni < 2; ++ni) { \
      bf[ni][0] = *(const bf16x8*)(smem + (BUFO) + bRowB + (NIH)*4096 + ni*2048 + cswz0); \
      bf[ni][1] = *(const bf16x8*)(smem + (BUFO) + bRowB + (NIH)*4096 + ni*2048 + cswz1); } }
#define MMQ(af, bf, MO, NO) { \
    __builtin_amdgcn_s_setprio(1); \
    _Pragma("unroll") for (int ni = 0; ni < 2; ++ni) \
    _Pragma("unroll") for (int mi = 0; mi < 4; ++mi) { \
      acc[(MO)+mi][(NO)+ni] = __builtin_amdgcn_mfma_f32_16x16x32_bf16(af[mi][0], bf[ni][0], acc[(MO)+mi][(NO)+ni], 0, 0, 0); \
      acc[(MO)+mi][(NO)+ni] = __builtin_amdgcn_mfma_f32_16x16x32_bf16(af[mi][1], bf[ni][1], acc[(MO)+mi][(NO)+ni], 0, 0, 0); } \
    __builtin_amdgcn_s_setprio(0); }
#define KTILE(KT, BO, NBO, W) { \
    RD_A(aL, BO, 0); RD_B(bL, BO, 0); \
    if ((KT) + 1 < NKT) ST_B(NBO, (KT) + 1, 0); \
    LGK8; \
    bar(); MMQ(aL, bL, 0, 0); bar(); \
    RD_A(aH, BO, 1); \
    if ((KT) + 1 < NKT) ST_B(NBO, (KT) + 1, 1); \
    bar(); MMQ(aH, bL, 4, 0); bar(); \
    RD_B(bH, BO, 1); \
    if ((KT) + 2 < NKT) ST_A(BO, (KT) + 2, 0); \
    bar(); MMQ(aH, bH, 4, 2); bar(); \
    if ((KT) + 2 < NKT) ST_A(BO, (KT) + 2, 1); \
    bar(); MMQ(aL, bH, 0, 2); \
    W; bar(); }

  ST_A(0, 0, 0); ST_A(0, 0, 1);
  ST_B(0, 0, 0); ST_B(0, 0, 1);
  ST_A(32768, 1, 0); ST_A(32768, 1, 1);
  VMW4; bar();

  // steady-state vmcnt(4); tail peeled (tile NKT-2 issues no A(NKT) -> full drain)
  for (int kt = 0; kt < NKT - 2; kt += 2) {
    KTILE(kt, 0, 32768, VMW4);
    KTILE(kt + 1, 32768, 0, VMW4);
  }
  KTILE(NKT - 2, 0, 32768, VMW0);
  KTILE(NKT - 1, 32768, 0, VMW0);

  if (OP == 0) {
    // in-register SwiGLU: gate in acc[.][even], up in acc[.][odd] (16-col interleave)
    bf16_t* Ho = kind ? O1 : O0;
    const int HN = kind ? SIDIM : IDIM;
    const int Lbase = n0 >> 1;
#pragma unroll
    for (int mi = 0; mi < 8; ++mi)
#pragma unroll
      for (int j = 0; j < 4; ++j) {
        int row = wr * 128 + mi * 16 + lg * 4 + j;
        int grow = row0 + row;
        if (kind == 0 && grow >= cnt) continue;
        size_t orow = (size_t)((kind ? 0 : slot0) + grow);
#pragma unroll
        for (int nih = 0; nih < 2; ++nih) {
          int Lr = wc * 32 + nih * 16 + lr;
          float g = acc[mi][2 * nih][j];
          float u = acc[mi][2 * nih + 1][j];
          if (kind) { g += bg[Lbase + Lr]; u += bu[Lbase + Lr]; }
          float h = (g / (1.f + __expf(-g))) * u;
          Ho[orow * HN + Lbase + Lr] = (bf16_t)h;
        }
      }
  } else {
    bf16_t* Po = kind ? (ks ? O2 : O1) : O0;
#pragma unroll
    for (int mi = 0; mi < 8; ++mi)
#pragma unroll
      for (int j = 0; j < 4; ++j) {
        int row = wr * 128 + mi * 16 + lg * 4 + j;
        int grow = row0 + row;
        if (kind == 0 && grow >= cnt) continue;
        size_t orow = (size_t)((kind ? 0 : slot0) + grow);
#pragma unroll
        for (int ni = 0; ni < 4; ++ni) {
          int col = n0 + wc * 64 + ni * 16 + lr;
          Po[orow * HDIM + col] = (bf16_t)acc[mi][ni][j];
        }
      }
  }
#undef ST_A
#undef ST_B
#undef RD_A
#undef RD_B
#undef MMQ
#undef KTILE
}

__global__ __launch_bounds__(512, 2)
void gu_gemm(const bf16_t* A0, const bf16_t* A1, const bf16_t* B0, const bf16_t* B1,
             bf16_t* O0, bf16_t* O1, bf16_t* O2, const float* bg, const float* bu,
             const int* meta, const int* tok_idx) {
  gemm8p_body<0>(A0, A1, B0, B1, O0, O1, O2, bg, bu, meta, tok_idx);
}
__global__ __launch_bounds__(512, 2)
void dn_gemm(const bf16_t* A0, const bf16_t* A1, const bf16_t* B0, const bf16_t* B1,
             bf16_t* O0, bf16_t* O1, bf16_t* O2, const float* bg, const float* bu,
             const int* meta, const int* tok_idx) {
  gemm8p_body<1>(A0, A1, B0, B1, O0, O1, O2, bg, bu, meta, tok_idx);
}

// out[t] = sh0[t]+sh1[t] + w1*rt[s1] + w2*rt[s2] + sdb
__global__ void combine_kernel(const bf16_t* __restrict__ sh0, const bf16_t* __restrict__ sh1,
                               const bf16_t* __restrict__ rt, const int* __restrict__ tk_slot,
                               const float* __restrict__ tk_w, const float* __restrict__ sdb,
                               float* __restrict__ out) {
  const int t = blockIdx.x;
  const int c = threadIdx.x * 8;
  const int s1 = tk_slot[2 * t], s2 = tk_slot[2 * t + 1];
  const float w1 = tk_w[2 * t], w2 = tk_w[2 * t + 1];
  bf16x8 a = *(const bf16x8*)(sh0 + (size_t)t * HDIM + c);
  bf16x8 b = *(const bf16x8*)(sh1 + (size_t)t * HDIM + c);
  bf16x8 r1 = *(const bf16x8*)(rt + (size_t)s1 * HDIM + c);
  bf16x8 r2 = *(const bf16x8*)(rt + (size_t)s2 * HDIM + c);
  float4 d0 = *(const float4*)(sdb + c);
  float4 d1 = *(const float4*)(sdb + c + 4);
  float o[8];
#pragma unroll
  for (int i = 0; i < 8; i++)
    o[i] = (float)a[i] + (float)b[i] + w1 * (float)r1[i] + w2 * (float)r2[i];
  o[0] += d0.x; o[1] += d0.y; o[2] += d0.z; o[3] += d0.w;
  o[4] += d1.x; o[5] += d1.y; o[6] += d1.z; o[7] += d1.w;
  float4* op = (float4*)(out + (size_t)t * HDIM + c);
  op[0] = make_float4(o[0], o[1], o[2], o[3]);
  op[1] = make_float4(o[4], o[5], o[6], o[7]);
}

extern "C" void kernel_launch(void* const* d_in, const int* in_sizes, int n_in,
                              void* d_out, int out_size, void* d_ws, size_t ws_size,
                              hipStream_t stream) {
  const float* x_f  = (const float*)d_in[0];
  const float* rw   = (const float*)d_in[1];
  const float* gate = (const float*)d_in[2];
  const float* up   = (const float*)d_in[3];
  const float* down = (const float*)d_in[4];
  const float* sgw  = (const float*)d_in[5];
  const float* sgb  = (const float*)d_in[6];
  const float* suw  = (const float*)d_in[7];
  const float* sub  = (const float*)d_in[8];
  const float* sdw  = (const float*)d_in[9];
  const float* sdb  = (const float*)d_in[10];
  float* out = (float*)d_out;

  char* ws = (char*)d_ws;
  size_t off = 0;
  auto alloc = [&](size_t bytes) {
    char* p = ws + off;
    off += (bytes + 255) & ~(size_t)255;
    return p;
  };
  bf16_t* xb    = (bf16_t*)alloc((size_t)T_TOK * HDIM * 2);
  char*   bgur  = alloc((size_t)NEXP * 2 * IDIM * HDIM * 2);            // 92.3MB
  bf16_t* BguR  = (bf16_t*)bgur;
  bf16_t* BguS  = (bf16_t*)alloc((size_t)2 * SIDIM * HDIM * 2);
  bf16_t* dT    = (bf16_t*)alloc((size_t)NEXP * HDIM * IDIM * 2);
  bf16_t* sdT   = (bf16_t*)alloc((size_t)HDIM * SIDIM * 2);
  bf16_t* hid_r = (bf16_t*)alloc((size_t)(T_TOK * 2) * IDIM * 2);
  bf16_t* hid_s = (bf16_t*)alloc((size_t)T_TOK * SIDIM * 2);
  int*    meta  = (int*)alloc(1024);
  int*    tok_idx = (int*)alloc(8192 * 4);
  int*    tk_slot = (int*)alloc(8192 * 4);
  int*    tk_i    = (int*)alloc((size_t)T_TOK * 2 * 4);
  float*  tk_w2   = (float*)alloc((size_t)T_TOK * 2 * 4);

  // down partials alias BguR (dead after gateup dispatch): 33.6+16.8+16.8 <= 92.3MB
  bf16_t* rt_p  = (bf16_t*)bgur;
  bf16_t* sh_p0 = (bf16_t*)(bgur + (size_t)8192 * HDIM * 2);
  bf16_t* sh_p1 = (bf16_t*)(bgur + (size_t)8192 * HDIM * 2 + (size_t)T_TOK * HDIM * 2);

  hipMemsetAsync(meta, 0, 64, stream);  // counts + cursor

  tcvt_all_kernel<<<21120, 256, 0, stream>>>(
      gate, up, sgw, suw, down, sdw, BguR, BguS, dT, sdT);

  router_kernel<<<T_TOK / 4, 256, 0, stream>>>(x_f, rw, xb, tk_i, tk_w2, meta);
  scatter_kernel<<<T_TOK / 256, 256, 0, stream>>>(tk_i, meta, tok_idx, tk_slot);

  gu_gemm<<<GU_CAP, 512, 0, stream>>>(
      xb, nullptr, BguR, BguS, hid_r, hid_s, nullptr, sgb, sub, meta, tok_idx);
  dn_gemm<<<DN_CAP, 512, 0, stream>>>(
      hid_r, hid_s, dT, sdT, rt_p, sh_p0, sh_p1, nullptr, nullptr, meta, nullptr);
  combine_kernel<<<T_TOK, 256, 0, stream>>>(sh_p0, sh_p1, rt_p, tk_slot, tk_w2, sdb, out);
}

// Round 15
// 550.159 us; speedup vs baseline: 1.5025x; 1.0338x over previous
//
#include <hip/hip_runtime.h>
#include <hip/hip_bf16.h>
#include <stdint.h>

#define T_TOK 4096
#define HDIM  2048
#define IDIM  1408
#define NEXP  8
#define SIDIM 2816
#define GU_CAP 781   // 39*11 + 352
#define DN_CAP 568   // 39*8 + 256 (uniform NKT=22 tiles)
#define RTR_BLKS 1024

typedef __bf16 bf16_t;
typedef __bf16 bf16x8 __attribute__((ext_vector_type(8)));
typedef __bf16 bf16x4 __attribute__((ext_vector_type(4)));
typedef float  f32x4  __attribute__((ext_vector_type(4)));

typedef uint32_t __attribute__((address_space(3))) lds_u32;
typedef uint32_t __attribute__((address_space(1))) glb_u32;

__device__ __forceinline__ void glds16(const bf16_t* g, const char* l) {
  __builtin_amdgcn_global_load_lds((const glb_u32*)g, (lds_u32*)l, 16, 0, 0);
}

__device__ __forceinline__ void bar() {
  asm volatile("" ::: "memory");
  __builtin_amdgcn_s_barrier();
  asm volatile("" ::: "memory");
}
#define VMW4 asm volatile("s_waitcnt vmcnt(4)" ::: "memory")
#define VMW0 asm volatile("s_waitcnt vmcnt(0)" ::: "memory")
#define LGK8 asm volatile("s_waitcnt lgkmcnt(8)" ::: "memory")

// m204 bijective XCD swizzle
__device__ __forceinline__ int xcd_swz(int orig, int nwg) {
  int q = nwg >> 3, r = nwg & 7;
  int x = orig & 7, i = orig >> 3;
  return (x < r ? x * (q + 1) : r * (q + 1) + (x - r) * q) + i;
}

// ---------------- merged: router (blocks 0..1023) + ALL weight transpose/convert ----------
// Router blocks first -> counts complete early inside the dispatch fill; tcvt jobs
// follow (thresholds shifted by RTR_BLKS). LDS granule XOR swizzle on tcvt path.
__global__ void prep_all_kernel(const float* __restrict__ x, const float* __restrict__ rw,
                                bf16_t* __restrict__ xb, int* __restrict__ tk_i,
                                float* __restrict__ tk_w, int* __restrict__ counts,
                                const float* __restrict__ gate, const float* __restrict__ up,
                                const float* __restrict__ sgw, const float* __restrict__ suw,
                                const float* __restrict__ down, const float* __restrict__ sdw,
                                bf16_t* __restrict__ BguR, bf16_t* __restrict__ BguS,
                                bf16_t* __restrict__ dT, bf16_t* __restrict__ sdT) {
  const int b = blockIdx.x;
  if (b < RTR_BLKS) {
    // ---------------- router (fused x f32->bf16 conversion) ----------------
    int gtid = b * 256 + threadIdx.x;
    int t = gtid >> 6, lane = gtid & 63;
    const float4* xr = (const float4*)(x + (size_t)t * HDIM);
    bf16x4* xo = (bf16x4*)(xb + (size_t)t * HDIM);
    float acc[NEXP];
#pragma unroll
    for (int e = 0; e < NEXP; e++) acc[e] = 0.f;
    for (int i = lane; i < HDIM / 4; i += 64) {
      float4 xv = xr[i];
      bf16x4 o;
      o[0] = (bf16_t)xv.x; o[1] = (bf16_t)xv.y; o[2] = (bf16_t)xv.z; o[3] = (bf16_t)xv.w;
      xo[i] = o;
#pragma unroll
      for (int e = 0; e < NEXP; e++) {
        float4 wv = ((const float4*)(rw + e * HDIM))[i];
        acc[e] += xv.x * wv.x + xv.y * wv.y + xv.z * wv.z + xv.w * wv.w;
      }
    }
#pragma unroll
    for (int e = 0; e < NEXP; e++)
#pragma unroll
      for (int off = 32; off; off >>= 1) acc[e] += __shfl_down(acc[e], off);
    if (lane == 0) {
      int i1 = 0; float m1 = acc[0];
#pragma unroll
      for (int e = 1; e < NEXP; e++) if (acc[e] > m1) { m1 = acc[e]; i1 = e; }
      int i2 = -1; float m2 = -1e30f;
#pragma unroll
      for (int e = 0; e < NEXP; e++) if (e != i1 && acc[e] > m2) { m2 = acc[e]; i2 = e; }
      float w1 = 1.f / (1.f + __expf(m2 - m1));
      tk_i[t * 2] = i1; tk_i[t * 2 + 1] = i2;
      tk_w[t * 2] = w1; tk_w[t * 2 + 1] = 1.f - w1;
      atomicAdd(&counts[i1], 1); atomicAdd(&counts[i2], 1);
    }
    return;
  }

  // ---------------- transpose+convert (64x64 tiles, f32 [R][C] -> bf16 [C][R]) ----------
  const int bb = b - RTR_BLKS;
  const float* in; bf16_t* out; int R, C, bx, by, which = 0; bool gu;
  if (bb < 11264) {                        // gu-routed: 16 z x 22 x x 32 y
    int z = bb / 704, rem = bb - z * 704;
    bx = rem % 22; by = rem / 22;
    int e = z >> 1; which = z & 1;
    in = (which ? up : gate) + (size_t)e * HDIM * IDIM;
    out = BguR + (size_t)e * (2 * IDIM) * HDIM;
    R = HDIM; C = IDIM; gu = true;
  } else if (bb < 14080) {                 // gu-shared: 2 z x 44 x x 32 y
    int k = bb - 11264;
    int z = k / 1408, rem = k - z * 1408;
    bx = rem % 44; by = rem / 44;
    which = z;
    in = which ? suw : sgw;
    out = BguS;
    R = HDIM; C = SIDIM; gu = true;
  } else if (bb < 19712) {                 // dT: 8 z x 32 x x 22 y
    int k = bb - 14080;
    int z = k / 704, rem = k - z * 704;
    bx = rem % 32; by = rem / 32;
    in = down + (size_t)z * IDIM * HDIM;
    out = dT + (size_t)z * HDIM * IDIM;
    R = IDIM; C = HDIM; gu = false;
  } else {                                 // sdT: 32 x x 44 y
    int k = bb - 19712;
    bx = k % 32; by = k / 32;
    in = sdw; out = sdT;
    R = SIDIM; C = HDIM; gu = false;
  }
  __shared__ float tf[64 * 64];
  const int r0 = by * 64, c0 = bx * 64;
  const int tid = threadIdx.x;
  const int cb = tid & 15, rr = tid >> 4;
#pragma unroll
  for (int s = 0; s < 4; ++s) {
    int r = rr + 16 * s;
    float4 v = *(const float4*)(in + (size_t)(r0 + r) * C + c0 + cb * 4);
    int slot = (cb ^ (r & 7) ^ ((r >> 4) << 1)) & 15;
    *(float4*)&tf[r * 64 + slot * 4] = v;
  }
  __syncthreads();
  const int c = tid >> 2, rb = (tid & 3) * 16;
  bf16x8 w0, w1;
#pragma unroll
  for (int i = 0; i < 16; ++i) {
    int r = rb + i;
    int slot = ((c >> 2) ^ (r & 7) ^ ((r >> 4) << 1)) & 15;
    float v = tf[r * 64 + slot * 4 + (c & 3)];
    if (i < 8) w0[i] = (bf16_t)v; else w1[i - 8] = (bf16_t)v;
  }
  int cg = c0 + c;
  int nprime = gu ? (((cg >> 4) << 5) + which * 16 + (cg & 15)) : cg;
  bf16_t* op = out + (size_t)nprime * R + r0 + rb;
  *(bf16x8*)op = w0;
  *(bf16x8*)(op + 8) = w1;
}

// ---------------- scatter: self-computed prefix ----------------
// meta: [0..7] counts (router), [8..15] cursor
__global__ void scatter_kernel(const int* __restrict__ tk_i,
                               int* __restrict__ meta, int* __restrict__ tok_idx,
                               int* __restrict__ tk_slot) {
  __shared__ int offs[NEXP];
  if (threadIdx.x < NEXP) {
    int o = 0;
    for (int i = 0; i < (int)threadIdx.x; ++i) o += meta[i];
    offs[threadIdx.x] = o;
  }
  __syncthreads();
  int t = blockIdx.x * 256 + threadIdx.x;
  if (t >= T_TOK) return;
#pragma unroll
  for (int k = 0; k < 2; k++) {
    int e = tk_i[t * 2 + k];
    int pos = offs[e] + atomicAdd(&meta[8 + e], 1);
    tok_idx[pos] = t; tk_slot[t * 2 + k] = pos;
  }
}

// ---------------- fused 8-phase 256x256 GEMM, SELF-DECODED tile table ----------------
// ROUND-5 schedule (proven): per phase {ds_read frags, stage, barrier, MMQ, barrier};
// counted vmcnt(4) steady-state, full drain on the peeled 2-tile tail.
template <int OP>
__device__ __forceinline__
void gemm8p_body(const bf16_t* __restrict__ A0, const bf16_t* __restrict__ A1,
                 const bf16_t* __restrict__ B0, const bf16_t* __restrict__ B1,
                 bf16_t* __restrict__ O0, bf16_t* __restrict__ O1, bf16_t* __restrict__ O2,
                 const float* __restrict__ bg, const float* __restrict__ bu,
                 const int* __restrict__ meta, const int* __restrict__ tok_idx) {
  // per-expert tile counts + prefix from counts[8]
  int nt[NEXP], offp[NEXP];
  int nmt = 0, osum = 0;
#pragma unroll
  for (int i = 0; i < NEXP; ++i) {
    offp[i] = osum; osum += meta[i];
    nt[i] = (meta[i] + 255) >> 8;
    nmt += nt[i];
  }
  const int ntiles = (OP == 0) ? (nmt * 11 + 352) : (nmt * 8 + 256);
  const int l = blockIdx.x;
  if (l >= ntiles) return;
  const int s = xcd_swz(l, ntiles);

  int kind, e = 0, row0, n0, ks = 0;
  if (OP == 0) {
    if (s < nmt * 11) {                      // routed, xt-paired (g<5), xt=10 singleton
      kind = 0;
      int g = s / (nmt * 2), rem = s - g * (nmt * 2);
      int yt, xt;
      if (g < 5) { yt = rem >> 1; xt = g * 2 + (rem & 1); }
      else       { yt = rem;      xt = 10; }
      int acc = 0, ytin = 0;
#pragma unroll
      for (int i = 0; i < NEXP; ++i) { if (yt >= acc) { e = i; ytin = yt - acc; } acc += nt[i]; }
      row0 = ytin << 8; n0 = xt * 256;
    } else {                                 // shared: 352 = 11 xt-pairs x 32
      kind = 1;
      int k = s - nmt * 11, g = k >> 5, rem = k & 31;
      row0 = (rem >> 1) * 256; n0 = (g * 2 + (rem & 1)) * 256;
    }
  } else {
    if (s < nmt * 8) {                       // routed, xt-paired
      kind = 0;
      int g = s / (nmt * 2), rem = s - g * (nmt * 2);
      int yt = rem >> 1, xt = g * 2 + (rem & 1);
      int acc = 0, ytin = 0;
#pragma unroll
      for (int i = 0; i < NEXP; ++i) { if (yt >= acc) { e = i; ytin = yt - acc; } acc += nt[i]; }
      row0 = ytin << 8; n0 = xt * 256;
    } else {                                 // shared: 256 = 8 xt x (2 ks x 16 yt)
      kind = 1;
      int k = s - nmt * 8;
      int xt = k >> 5, rem = k & 31;
      ks = rem >> 4;
      row0 = (rem & 15) * 256; n0 = xt * 256;
    }
  }

  int cnt, slot0 = 0, strideA, strideB, koff = 0;
  const bf16_t *Ab, *Bp;
  constexpr int NKT = (OP == 0) ? (HDIM / 64) : (IDIM / 64);  // 32 | 22
  if (OP == 0) {
    strideA = HDIM; strideB = HDIM; Ab = A0;
    if (kind == 0) {
      slot0 = offp[e]; cnt = meta[e];
      Bp = B0 + (size_t)e * (2 * IDIM) * HDIM;
    } else { cnt = T_TOK; Bp = B1; }
  } else {
    if (kind == 0) {
      slot0 = offp[e]; cnt = meta[e];
      Ab = A0; strideA = IDIM;
      Bp = B0 + (size_t)e * HDIM * IDIM; strideB = IDIM;
    } else {
      cnt = T_TOK; Ab = A1; strideA = SIDIM;
      Bp = B1; strideB = SIDIM; koff = ks * IDIM;
    }
  }

  __shared__ __align__(16) char smem[131072];

  const int t = threadIdx.x;
  const int lane = t & 63, wid = t >> 6;
  const int wr = wid >> 2, wc = wid & 3;
  const int lr = lane & 15, lg = lane >> 4;

  const bf16_t* pA[4]; const bf16_t* pB[4]; int dG[4];
#pragma unroll
  for (int j = 0; j < 4; ++j) {
    int g = j * 512 + t;
    int r = g >> 3;
    int c16 = (g & 7) ^ (r & 7);
    dG[j] = g * 16;
    int rr = row0 + r;
    if (kind == 0 && rr >= cnt) rr = cnt - 1;
    int arow;
    if (OP == 0 && kind == 0) arow = tok_idx[slot0 + rr];
    else if (OP == 1 && kind == 0) arow = slot0 + rr;
    else arow = rr;
    pA[j] = Ab + (size_t)arow * strideA + koff + c16 * 8;
    pB[j] = Bp + (size_t)(n0 + r) * strideB + koff + c16 * 8;
  }

  const int cswz0 = ((lg) ^ (lr & 7)) * 16;
  const int cswz1 = ((4 + lg) ^ (lr & 7)) * 16;
  const int aRowB = (wr * 128 + lr) * 128;
  const int bRowB = (wc * 64 + lr) * 128 + 65536;

  f32x4 acc[8][4];
#pragma unroll
  for (int mi = 0; mi < 8; ++mi)
#pragma unroll
    for (int ni = 0; ni < 4; ++ni) acc[mi][ni] = (f32x4)(0.f);

  bf16x8 aL[4][2], aH[4][2], bL[2][2], bH[2][2];

#define ST_A(BUFO, KT, JH) { \
    glds16(pA[(JH)*2]   + (KT)*64, smem + (BUFO) + dG[(JH)*2]); \
    glds16(pA[(JH)*2+1] + (KT)*64, smem + (BUFO) + dG[(JH)*2+1]); }
#define ST_B(BUFO, KT, JH) { \
    glds16(pB[(JH)*2]   + (KT)*64, smem + 65536 + (BUFO) + dG[(JH)*2]); \
    glds16(pB[(JH)*2+1] + (KT)*64, smem + 65536 + (BUFO) + dG[(JH)*2+1]); }
#define RD_A(af, BUFO, MIH) { \
    _Pragma("unroll") for (int mi = 0; mi < 4; ++mi) { \
      af[mi][0] = *(const bf16x8*)(smem + (BUFO) + aRowB + (MIH)*8192 + mi*2048 + cswz0); \
      af[mi][1] = *(const bf16x8*)(smem + (BUFO) + aRowB + (MIH)*8192 + mi*2048 + cswz1); } }
#define RD_B(bf, BUFO, NIH) { \
    _Pragma("unroll") for (int ni = 0; ni < 2; ++ni) { \
      bf[ni][0] = *(const bf16x8*)(smem + (BUFO) + bRowB + (NIH)*4096 + ni*2048 + cswz0); \
      bf[ni][1] = *(const bf16x8*)(smem + (BUFO) + bRowB + (NIH)*4096 + ni*2048 + cswz1); } }
#define MMQ(af, bf, MO, NO) { \
    __builtin_amdgcn_s_setprio(1); \
    _Pragma("unroll") for (int ni = 0; ni < 2; ++ni) \
    _Pragma("unroll") for (int mi = 0; mi < 4; ++mi) { \
      acc[(MO)+mi][(NO)+ni] = __builtin_amdgcn_mfma_f32_16x16x32_bf16(af[mi][0], bf[ni][0], acc[(MO)+mi][(NO)+ni], 0, 0, 0); \
      acc[(MO)+mi][(NO)+ni] = __builtin_amdgcn_mfma_f32_16x16x32_bf16(af[mi][1], bf[ni][1], acc[(MO)+mi][(NO)+ni], 0, 0, 0); } \
    __builtin_amdgcn_s_setprio(0); }
#define KTILE(KT, BO, NBO, W) { \
    RD_A(aL, BO, 0); RD_B(bL, BO, 0); \
    if ((KT) + 1 < NKT) ST_B(NBO, (KT) + 1, 0); \
    LGK8; \
    bar(); MMQ(aL, bL, 0, 0); bar(); \
    RD_A(aH, BO, 1); \
    if ((KT) + 1 < NKT) ST_B(NBO, (KT) + 1, 1); \
    bar(); MMQ(aH, bL, 4, 0); bar(); \
    RD_B(bH, BO, 1); \
    if ((KT) + 2 < NKT) ST_A(BO, (KT) + 2, 0); \
    bar(); MMQ(aH, bH, 4, 2); bar(); \
    if ((KT) + 2 < NKT) ST_A(BO, (KT) + 2, 1); \
    bar(); MMQ(aL, bH, 0, 2); \
    W; bar(); }

  ST_A(0, 0, 0); ST_A(0, 0, 1);
  ST_B(0, 0, 0); ST_B(0, 0, 1);
  ST_A(32768, 1, 0); ST_A(32768, 1, 1);
  VMW4; bar();

  // steady-state vmcnt(4); tail peeled (tile NKT-2 issues no A(NKT) -> full drain)
  for (int kt = 0; kt < NKT - 2; kt += 2) {
    KTILE(kt, 0, 32768, VMW4);
    KTILE(kt + 1, 32768, 0, VMW4);
  }
  KTILE(NKT - 2, 0, 32768, VMW0);
  KTILE(NKT - 1, 32768, 0, VMW0);

  if (OP == 0) {
    // in-register SwiGLU: gate in acc[.][even], up in acc[.][odd] (16-col interleave)
    bf16_t* Ho = kind ? O1 : O0;
    const int HN = kind ? SIDIM : IDIM;
    const int Lbase = n0 >> 1;
#pragma unroll
    for (int mi = 0; mi < 8; ++mi)
#pragma unroll
      for (int j = 0; j < 4; ++j) {
        int row = wr * 128 + mi * 16 + lg * 4 + j;
        int grow = row0 + row;
        if (kind == 0 && grow >= cnt) continue;
        size_t orow = (size_t)((kind ? 0 : slot0) + grow);
#pragma unroll
        for (int nih = 0; nih < 2; ++nih) {
          int Lr = wc * 32 + nih * 16 + lr;
          float g = acc[mi][2 * nih][j];
          float u = acc[mi][2 * nih + 1][j];
          if (kind) { g += bg[Lbase + Lr]; u += bu[Lbase + Lr]; }
          float h = (g / (1.f + __expf(-g))) * u;
          Ho[orow * HN + Lbase + Lr] = (bf16_t)h;
        }
      }
  } else {
    bf16_t* Po = kind ? (ks ? O2 : O1) : O0;
#pragma unroll
    for (int mi = 0; mi < 8; ++mi)
#pragma unroll
      for (int j = 0; j < 4; ++j) {
        int row = wr * 128 + mi * 16 + lg * 4 + j;
        int grow = row0 + row;
        if (kind == 0 && grow >= cnt) continue;
        size_t orow = (size_t)((kind ? 0 : slot0) + grow);
#pragma unroll
        for (int ni = 0; ni < 4; ++ni) {
          int col = n0 + wc * 64 + ni * 16 + lr;
          Po[orow * HDIM + col] = (bf16_t)acc[mi][ni][j];
        }
      }
  }
#undef ST_A
#undef ST_B
#undef RD_A
#undef RD_B
#undef MMQ
#undef KTILE
}

__global__ __launch_bounds__(512, 2)
void gu_gemm(const bf16_t* A0, const bf16_t* A1, const bf16_t* B0, const bf16_t* B1,
             bf16_t* O0, bf16_t* O1, bf16_t* O2, const float* bg, const float* bu,
             const int* meta, const int* tok_idx) {
  gemm8p_body<0>(A0, A1, B0, B1, O0, O1, O2, bg, bu, meta, tok_idx);
}
__global__ __launch_bounds__(512, 2)
void dn_gemm(const bf16_t* A0, const bf16_t* A1, const bf16_t* B0, const bf16_t* B1,
             bf16_t* O0, bf16_t* O1, bf16_t* O2, const float* bg, const float* bu,
             const int* meta, const int* tok_idx) {
  gemm8p_body<1>(A0, A1, B0, B1, O0, O1, O2, bg, bu, meta, tok_idx);
}

// out[t] = sh0[t]+sh1[t] + w1*rt[s1] + w2*rt[s2] + sdb
__global__ void combine_kernel(const bf16_t* __restrict__ sh0, const bf16_t* __restrict__ sh1,
                               const bf16_t* __restrict__ rt, const int* __restrict__ tk_slot,
                               const float* __restrict__ tk_w, const float* __restrict__ sdb,
                               float* __restrict__ out) {
  const int t = blockIdx.x;
  const int c = threadIdx.x * 8;
  const int s1 = tk_slot[2 * t], s2 = tk_slot[2 * t + 1];
  const float w1 = tk_w[2 * t], w2 = tk_w[2 * t + 1];
  bf16x8 a = *(const bf16x8*)(sh0 + (size_t)t * HDIM + c);
  bf16x8 b = *(const bf16x8*)(sh1 + (size_t)t * HDIM + c);
  bf16x8 r1 = *(const bf16x8*)(rt + (size_t)s1 * HDIM + c);
  bf16x8 r2 = *(const bf16x8*)(rt + (size_t)s2 * HDIM + c);
  float4 d0 = *(const float4*)(sdb + c);
  float4 d1 = *(const float4*)(sdb + c + 4);
  float o[8];
#pragma unroll
  for (int i = 0; i < 8; i++)
    o[i] = (float)a[i] + (float)b[i] + w1 * (float)r1[i] + w2 * (float)r2[i];
  o[0] += d0.x; o[1] += d0.y; o[2] += d0.z; o[3] += d0.w;
  o[4] += d1.x; o[5] += d1.y; o[6] += d1.z; o[7] += d1.w;
  float4* op = (float4*)(out + (size_t)t * HDIM + c);
  op[0] = make_float4(o[0], o[1], o[2], o[3]);
  op[1] = make_float4(o[4], o[5], o[6], o[7]);
}

extern "C" void kernel_launch(void* const* d_in, const int* in_sizes, int n_in,
                              void* d_out, int out_size, void* d_ws, size_t ws_size,
                              hipStream_t stream) {
  const float* x_f  = (const float*)d_in[0];
  const float* rw   = (const float*)d_in[1];
  const float* gate = (const float*)d_in[2];
  const float* up   = (const float*)d_in[3];
  const float* down = (const float*)d_in[4];
  const float* sgw  = (const float*)d_in[5];
  const float* sgb  = (const float*)d_in[6];
  const float* suw  = (const float*)d_in[7];
  const float* sub  = (const float*)d_in[8];
  const float* sdw  = (const float*)d_in[9];
  const float* sdb  = (const float*)d_in[10];
  float* out = (float*)d_out;

  char* ws = (char*)d_ws;
  size_t off = 0;
  auto alloc = [&](size_t bytes) {
    char* p = ws + off;
    off += (bytes + 255) & ~(size_t)255;
    return p;
  };
  bf16_t* xb    = (bf16_t*)alloc((size_t)T_TOK * HDIM * 2);
  char*   bgur  = alloc((size_t)NEXP * 2 * IDIM * HDIM * 2);            // 92.3MB
  bf16_t* BguR  = (bf16_t*)bgur;
  bf16_t* BguS  = (bf16_t*)alloc((size_t)2 * SIDIM * HDIM * 2);
  bf16_t* dT    = (bf16_t*)alloc((size_t)NEXP * HDIM * IDIM * 2);
  bf16_t* sdT   = (bf16_t*)alloc((size_t)HDIM * SIDIM * 2);
  bf16_t* hid_r = (bf16_t*)alloc((size_t)(T_TOK * 2) * IDIM * 2);
  bf16_t* hid_s = (bf16_t*)alloc((size_t)T_TOK * SIDIM * 2);
  int*    meta  = (int*)alloc(1024);
  int*    tok_idx = (int*)alloc(8192 * 4);
  int*    tk_slot = (int*)alloc(8192 * 4);
  int*    tk_i    = (int*)alloc((size_t)T_TOK * 2 * 4);
  float*  tk_w2   = (float*)alloc((size_t)T_TOK * 2 * 4);

  // down partials alias BguR (dead after gateup dispatch): 33.6+16.8+16.8 <= 92.3MB
  bf16_t* rt_p  = (bf16_t*)bgur;
  bf16_t* sh_p0 = (bf16_t*)(bgur + (size_t)8192 * HDIM * 2);
  bf16_t* sh_p1 = (bf16_t*)(bgur + (size_t)8192 * HDIM * 2 + (size_t)T_TOK * HDIM * 2);

  hipMemsetAsync(meta, 0, 64, stream);  // counts + cursor

  prep_all_kernel<<<RTR_BLKS + 21120, 256, 0, stream>>>(
      x_f, rw, xb, tk_i, tk_w2, meta,
      gate, up, sgw, suw, down, sdw, BguR, BguS, dT, sdT);

  scatter_kernel<<<T_TOK / 256, 256, 0, stream>>>(tk_i, meta, tok_idx, tk_slot);

  gu_gemm<<<GU_CAP, 512, 0, stream>>>(
      xb, nullptr, BguR, BguS, hid_r, hid_s, nullptr, sgb, sub, meta, tok_idx);
  dn_gemm<<<DN_CAP, 512, 0, stream>>>(
      hid_r, hid_s, dT, sdT, rt_p, sh_p0, sh_p1, nullptr, nullptr, meta, nullptr);
  combine_kernel<<<T_TOK, 256, 0, stream>>>(sh_p0, sh_p1, rt_p, tk_slot, tk_w2, sdb, out);
}

// Round 16
// 548.383 us; speedup vs baseline: 1.5074x; 1.0032x over previous
//
#include <hip/hip_runtime.h>
#include <hip/hip_bf16.h>
#include <stdint.h>

#define T_TOK 4096
#define HDIM  2048
#define IDIM  1408
#define NEXP  8
#define SIDIM 2816
#define GU_CAP 781   // 39*11 + 352
#define DN_CAP 568   // 39*8 + 256 (uniform NKT=22 tiles)
#define RTR_BLKS 1024

typedef __bf16 bf16_t;
typedef __bf16 bf16x8 __attribute__((ext_vector_type(8)));
typedef __bf16 bf16x4 __attribute__((ext_vector_type(4)));
typedef float  f32x4  __attribute__((ext_vector_type(4)));

typedef uint32_t __attribute__((address_space(3))) lds_u32;
typedef uint32_t __attribute__((address_space(1))) glb_u32;

__device__ __forceinline__ void glds16(const bf16_t* g, const char* l) {
  __builtin_amdgcn_global_load_lds((const glb_u32*)g, (lds_u32*)l, 16, 0, 0);
}

__device__ __forceinline__ void bar() {
  asm volatile("" ::: "memory");
  __builtin_amdgcn_s_barrier();
  asm volatile("" ::: "memory");
}
#define VMW4 asm volatile("s_waitcnt vmcnt(4)" ::: "memory")
#define VMW0 asm volatile("s_waitcnt vmcnt(0)" ::: "memory")

// m204 bijective XCD swizzle
__device__ __forceinline__ int xcd_swz(int orig, int nwg) {
  int q = nwg >> 3, r = nwg & 7;
  int x = orig & 7, i = orig >> 3;
  return (x < r ? x * (q + 1) : r * (q + 1) + (x - r) * q) + i;
}

// ---------------- merged: router (blocks 0..1023) + ALL weight transpose/convert ----------
// Router blocks first -> counts complete early inside the dispatch fill; tcvt jobs
// follow (thresholds shifted by RTR_BLKS). LDS granule XOR swizzle on tcvt path.
__global__ void prep_all_kernel(const float* __restrict__ x, const float* __restrict__ rw,
                                bf16_t* __restrict__ xb, int* __restrict__ tk_i,
                                float* __restrict__ tk_w, int* __restrict__ counts,
                                const float* __restrict__ gate, const float* __restrict__ up,
                                const float* __restrict__ sgw, const float* __restrict__ suw,
                                const float* __restrict__ down, const float* __restrict__ sdw,
                                bf16_t* __restrict__ BguR, bf16_t* __restrict__ BguS,
                                bf16_t* __restrict__ dT, bf16_t* __restrict__ sdT) {
  const int b = blockIdx.x;
  if (b < RTR_BLKS) {
    // ---------------- router (fused x f32->bf16 conversion) ----------------
    int gtid = b * 256 + threadIdx.x;
    int t = gtid >> 6, lane = gtid & 63;
    const float4* xr = (const float4*)(x + (size_t)t * HDIM);
    bf16x4* xo = (bf16x4*)(xb + (size_t)t * HDIM);
    float acc[NEXP];
#pragma unroll
    for (int e = 0; e < NEXP; e++) acc[e] = 0.f;
    for (int i = lane; i < HDIM / 4; i += 64) {
      float4 xv = xr[i];
      bf16x4 o;
      o[0] = (bf16_t)xv.x; o[1] = (bf16_t)xv.y; o[2] = (bf16_t)xv.z; o[3] = (bf16_t)xv.w;
      xo[i] = o;
#pragma unroll
      for (int e = 0; e < NEXP; e++) {
        float4 wv = ((const float4*)(rw + e * HDIM))[i];
        acc[e] += xv.x * wv.x + xv.y * wv.y + xv.z * wv.z + xv.w * wv.w;
      }
    }
#pragma unroll
    for (int e = 0; e < NEXP; e++)
#pragma unroll
      for (int off = 32; off; off >>= 1) acc[e] += __shfl_down(acc[e], off);
    if (lane == 0) {
      int i1 = 0; float m1 = acc[0];
#pragma unroll
      for (int e = 1; e < NEXP; e++) if (acc[e] > m1) { m1 = acc[e]; i1 = e; }
      int i2 = -1; float m2 = -1e30f;
#pragma unroll
      for (int e = 0; e < NEXP; e++) if (e != i1 && acc[e] > m2) { m2 = acc[e]; i2 = e; }
      float w1 = 1.f / (1.f + __expf(m2 - m1));
      tk_i[t * 2] = i1; tk_i[t * 2 + 1] = i2;
      tk_w[t * 2] = w1; tk_w[t * 2 + 1] = 1.f - w1;
      atomicAdd(&counts[i1], 1); atomicAdd(&counts[i2], 1);
    }
    return;
  }

  // ---------------- transpose+convert (64x64 tiles, f32 [R][C] -> bf16 [C][R]) ----------
  const int bb = b - RTR_BLKS;
  const float* in; bf16_t* out; int R, C, bx, by, which = 0; bool gu;
  if (bb < 11264) {                        // gu-routed: 16 z x 22 x x 32 y
    int z = bb / 704, rem = bb - z * 704;
    bx = rem % 22; by = rem / 22;
    int e = z >> 1; which = z & 1;
    in = (which ? up : gate) + (size_t)e * HDIM * IDIM;
    out = BguR + (size_t)e * (2 * IDIM) * HDIM;
    R = HDIM; C = IDIM; gu = true;
  } else if (bb < 14080) {                 // gu-shared: 2 z x 44 x x 32 y
    int k = bb - 11264;
    int z = k / 1408, rem = k - z * 1408;
    bx = rem % 44; by = rem / 44;
    which = z;
    in = which ? suw : sgw;
    out = BguS;
    R = HDIM; C = SIDIM; gu = true;
  } else if (bb < 19712) {                 // dT: 8 z x 32 x x 22 y
    int k = bb - 14080;
    int z = k / 704, rem = k - z * 704;
    bx = rem % 32; by = rem / 32;
    in = down + (size_t)z * IDIM * HDIM;
    out = dT + (size_t)z * HDIM * IDIM;
    R = IDIM; C = HDIM; gu = false;
  } else {                                 // sdT: 32 x x 44 y
    int k = bb - 19712;
    bx = k % 32; by = k / 32;
    in = sdw; out = sdT;
    R = SIDIM; C = HDIM; gu = false;
  }
  __shared__ float tf[64 * 64];
  const int r0 = by * 64, c0 = bx * 64;
  const int tid = threadIdx.x;
  const int cb = tid & 15, rr = tid >> 4;
#pragma unroll
  for (int s = 0; s < 4; ++s) {
    int r = rr + 16 * s;
    float4 v = *(const float4*)(in + (size_t)(r0 + r) * C + c0 + cb * 4);
    int slot = (cb ^ (r & 7) ^ ((r >> 4) << 1)) & 15;
    *(float4*)&tf[r * 64 + slot * 4] = v;
  }
  __syncthreads();
  const int c = tid >> 2, rb = (tid & 3) * 16;
  bf16x8 w0, w1;
#pragma unroll
  for (int i = 0; i < 16; ++i) {
    int r = rb + i;
    int slot = ((c >> 2) ^ (r & 7) ^ ((r >> 4) << 1)) & 15;
    float v = tf[r * 64 + slot * 4 + (c & 3)];
    if (i < 8) w0[i] = (bf16_t)v; else w1[i - 8] = (bf16_t)v;
  }
  int cg = c0 + c;
  int nprime = gu ? (((cg >> 4) << 5) + which * 16 + (cg & 15)) : cg;
  bf16_t* op = out + (size_t)nprime * R + r0 + rb;
  *(bf16x8*)op = w0;
  *(bf16x8*)(op + 8) = w1;
}

// ---------------- scatter: self-computed prefix ----------------
// meta: [0..7] counts (router), [8..15] cursor
__global__ void scatter_kernel(const int* __restrict__ tk_i,
                               int* __restrict__ meta, int* __restrict__ tok_idx,
                               int* __restrict__ tk_slot) {
  __shared__ int offs[NEXP];
  if (threadIdx.x < NEXP) {
    int o = 0;
    for (int i = 0; i < (int)threadIdx.x; ++i) o += meta[i];
    offs[threadIdx.x] = o;
  }
  __syncthreads();
  int t = blockIdx.x * 256 + threadIdx.x;
  if (t >= T_TOK) return;
#pragma unroll
  for (int k = 0; k < 2; k++) {
    int e = tk_i[t * 2 + k];
    int pos = offs[e] + atomicAdd(&meta[8 + e], 1);
    tok_idx[pos] = t; tk_slot[t * 2 + k] = pos;
  }
}

// ---------------- fused 8-phase 256x256 GEMM, SELF-DECODED tile table ----------------
// ROUND-5 schedule (proven): per phase {ds_read frags, stage, barrier, MMQ, barrier};
// counted vmcnt(4) steady-state, full drain on the peeled 2-tile tail.
template <int OP>
__device__ __forceinline__
void gemm8p_body(const bf16_t* __restrict__ A0, const bf16_t* __restrict__ A1,
                 const bf16_t* __restrict__ B0, const bf16_t* __restrict__ B1,
                 bf16_t* __restrict__ O0, bf16_t* __restrict__ O1, bf16_t* __restrict__ O2,
                 const float* __restrict__ bg, const float* __restrict__ bu,
                 const int* __restrict__ meta, const int* __restrict__ tok_idx) {
  // per-expert tile counts + prefix from counts[8]
  int nt[NEXP], offp[NEXP];
  int nmt = 0, osum = 0;
#pragma unroll
  for (int i = 0; i < NEXP; ++i) {
    offp[i] = osum; osum += meta[i];
    nt[i] = (meta[i] + 255) >> 8;
    nmt += nt[i];
  }
  const int ntiles = (OP == 0) ? (nmt * 11 + 352) : (nmt * 8 + 256);
  const int l = blockIdx.x;
  if (l >= ntiles) return;
  const int s = xcd_swz(l, ntiles);

  int kind, e = 0, row0, n0, ks = 0;
  if (OP == 0) {
    if (s < nmt * 11) {                      // routed, xt-paired (g<5), xt=10 singleton
      kind = 0;
      int g = s / (nmt * 2), rem = s - g * (nmt * 2);
      int yt, xt;
      if (g < 5) { yt = rem >> 1; xt = g * 2 + (rem & 1); }
      else       { yt = rem;      xt = 10; }
      int acc = 0, ytin = 0;
#pragma unroll
      for (int i = 0; i < NEXP; ++i) { if (yt >= acc) { e = i; ytin = yt - acc; } acc += nt[i]; }
      row0 = ytin << 8; n0 = xt * 256;
    } else {                                 // shared: 352 = 11 xt-pairs x 32
      kind = 1;
      int k = s - nmt * 11, g = k >> 5, rem = k & 31;
      row0 = (rem >> 1) * 256; n0 = (g * 2 + (rem & 1)) * 256;
    }
  } else {
    if (s < nmt * 8) {                       // routed, xt-paired
      kind = 0;
      int g = s / (nmt * 2), rem = s - g * (nmt * 2);
      int yt = rem >> 1, xt = g * 2 + (rem & 1);
      int acc = 0, ytin = 0;
#pragma unroll
      for (int i = 0; i < NEXP; ++i) { if (yt >= acc) { e = i; ytin = yt - acc; } acc += nt[i]; }
      row0 = ytin << 8; n0 = xt * 256;
    } else {                                 // shared: 256 = 8 xt x (2 ks x 16 yt)
      kind = 1;
      int k = s - nmt * 8;
      int xt = k >> 5, rem = k & 31;
      ks = rem >> 4;
      row0 = (rem & 15) * 256; n0 = xt * 256;
    }
  }

  int cnt, slot0 = 0, strideA, strideB, koff = 0;
  const bf16_t *Ab, *Bp;
  constexpr int NKT = (OP == 0) ? (HDIM / 64) : (IDIM / 64);  // 32 | 22
  if (OP == 0) {
    strideA = HDIM; strideB = HDIM; Ab = A0;
    if (kind == 0) {
      slot0 = offp[e]; cnt = meta[e];
      Bp = B0 + (size_t)e * (2 * IDIM) * HDIM;
    } else { cnt = T_TOK; Bp = B1; }
  } else {
    if (kind == 0) {
      slot0 = offp[e]; cnt = meta[e];
      Ab = A0; strideA = IDIM;
      Bp = B0 + (size_t)e * HDIM * IDIM; strideB = IDIM;
    } else {
      cnt = T_TOK; Ab = A1; strideA = SIDIM;
      Bp = B1; strideB = SIDIM; koff = ks * IDIM;
    }
  }

  __shared__ __align__(16) char smem[131072];

  const int t = threadIdx.x;
  const int lane = t & 63, wid = t >> 6;
  const int wr = wid >> 2, wc = wid & 3;
  const int lr = lane & 15, lg = lane >> 4;

  const bf16_t* pA[4]; const bf16_t* pB[4]; int dG[4];
#pragma unroll
  for (int j = 0; j < 4; ++j) {
    int g = j * 512 + t;
    int r = g >> 3;
    int c16 = (g & 7) ^ (r & 7);
    dG[j] = g * 16;
    int rr = row0 + r;
    if (kind == 0 && rr >= cnt) rr = cnt - 1;
    int arow;
    if (OP == 0 && kind == 0) arow = tok_idx[slot0 + rr];
    else if (OP == 1 && kind == 0) arow = slot0 + rr;
    else arow = rr;
    pA[j] = Ab + (size_t)arow * strideA + koff + c16 * 8;
    pB[j] = Bp + (size_t)(n0 + r) * strideB + koff + c16 * 8;
  }

  const int cswz0 = ((lg) ^ (lr & 7)) * 16;
  const int cswz1 = ((4 + lg) ^ (lr & 7)) * 16;
  const int aRowB = (wr * 128 + lr) * 128;
  const int bRowB = (wc * 64 + lr) * 128 + 65536;

  f32x4 acc[8][4];
#pragma unroll
  for (int mi = 0; mi < 8; ++mi)
#pragma unroll
    for (int ni = 0; ni < 4; ++ni) acc[mi][ni] = (f32x4)(0.f);

  bf16x8 aL[4][2], aH[4][2], bL[2][2], bH[2][2];

#define ST_A(BUFO, KT, JH) { \
    glds16(pA[(JH)*2]   + (KT)*64, smem + (BUFO) + dG[(JH)*2]); \
    glds16(pA[(JH)*2+1] + (KT)*64, smem + (BUFO) + dG[(JH)*2+1]); }
#define ST_B(BUFO, KT, JH) { \
    glds16(pB[(JH)*2]   + (KT)*64, smem + 65536 + (BUFO) + dG[(JH)*2]); \
    glds16(pB[(JH)*2+1] + (KT)*64, smem + 65536 + (BUFO) + dG[(JH)*2+1]); }
#define RD_A(af, BUFO, MIH) { \
    _Pragma("unroll") for (int mi = 0; mi < 4; ++mi) { \
      af[mi][0] = *(const bf16x8*)(smem + (BUFO) + aRowB + (MIH)*8192 + mi*2048 + cswz0); \
      af[mi][1] = *(const bf16x8*)(smem + (BUFO) + aRowB + (MIH)*8192 + mi*2048 + cswz1); } }
#define RD_B(bf, BUFO, NIH) { \
    _Pragma("unroll") for (int ni = 0; ni < 2; ++ni) { \
      bf[ni][0] = *(const bf16x8*)(smem + (BUFO) + bRowB + (NIH)*4096 + ni*2048 + cswz0); \
      bf[ni][1] = *(const bf16x8*)(smem + (BUFO) + bRowB + (NIH)*4096 + ni*2048 + cswz1); } }
#define MMQ(af, bf, MO, NO) { \
    __builtin_amdgcn_s_setprio(1); \
    _Pragma("unroll") for (int ni = 0; ni < 2; ++ni) \
    _Pragma("unroll") for (int mi = 0; mi < 4; ++mi) { \
      acc[(MO)+mi][(NO)+ni] = __builtin_amdgcn_mfma_f32_16x16x32_bf16(af[mi][0], bf[ni][0], acc[(MO)+mi][(NO)+ni], 0, 0, 0); \
      acc[(MO)+mi][(NO)+ni] = __builtin_amdgcn_mfma_f32_16x16x32_bf16(af[mi][1], bf[ni][1], acc[(MO)+mi][(NO)+ni], 0, 0, 0); } \
    __builtin_amdgcn_s_setprio(0); }
#define KTILE(KT, BO, NBO, W) { \
    RD_A(aL, BO, 0); RD_B(bL, BO, 0); \
    if ((KT) + 1 < NKT) ST_B(NBO, (KT) + 1, 0); \
    bar(); MMQ(aL, bL, 0, 0); bar(); \
    RD_A(aH, BO, 1); \
    if ((KT) + 1 < NKT) ST_B(NBO, (KT) + 1, 1); \
    bar(); MMQ(aH, bL, 4, 0); bar(); \
    RD_B(bH, BO, 1); \
    if ((KT) + 2 < NKT) ST_A(BO, (KT) + 2, 0); \
    bar(); MMQ(aH, bH, 4, 2); bar(); \
    if ((KT) + 2 < NKT) ST_A(BO, (KT) + 2, 1); \
    bar(); MMQ(aL, bH, 0, 2); \
    W; bar(); }

  ST_A(0, 0, 0); ST_A(0, 0, 1);
  ST_B(0, 0, 0); ST_B(0, 0, 1);
  ST_A(32768, 1, 0); ST_A(32768, 1, 1);
  VMW4; bar();

  // steady-state vmcnt(4); tail peeled (tile NKT-2 issues no A(NKT) -> full drain)
  for (int kt = 0; kt < NKT - 2; kt += 2) {
    KTILE(kt, 0, 32768, VMW4);
    KTILE(kt + 1, 32768, 0, VMW4);
  }
  KTILE(NKT - 2, 0, 32768, VMW0);
  KTILE(NKT - 1, 32768, 0, VMW0);

  if (OP == 0) {
    // in-register SwiGLU: gate in acc[.][even], up in acc[.][odd] (16-col interleave)
    bf16_t* Ho = kind ? O1 : O0;
    const int HN = kind ? SIDIM : IDIM;
    const int Lbase = n0 >> 1;
#pragma unroll
    for (int mi = 0; mi < 8; ++mi)
#pragma unroll
      for (int j = 0; j < 4; ++j) {
        int row = wr * 128 + mi * 16 + lg * 4 + j;
        int grow = row0 + row;
        if (kind == 0 && grow >= cnt) continue;
        size_t orow = (size_t)((kind ? 0 : slot0) + grow);
#pragma unroll
        for (int nih = 0; nih < 2; ++nih) {
          int Lr = wc * 32 + nih * 16 + lr;
          float g = acc[mi][2 * nih][j];
          float u = acc[mi][2 * nih + 1][j];
          if (kind) { g += bg[Lbase + Lr]; u += bu[Lbase + Lr]; }
          float h = (g / (1.f + __expf(-g))) * u;
          Ho[orow * HN + Lbase + Lr] = (bf16_t)h;
        }
      }
  } else {
    bf16_t* Po = kind ? (ks ? O2 : O1) : O0;
#pragma unroll
    for (int mi = 0; mi < 8; ++mi)
#pragma unroll
      for (int j = 0; j < 4; ++j) {
        int row = wr * 128 + mi * 16 + lg * 4 + j;
        int grow = row0 + row;
        if (kind == 0 && grow >= cnt) continue;
        size_t orow = (size_t)((kind ? 0 : slot0) + grow);
#pragma unroll
        for (int ni = 0; ni < 4; ++ni) {
          int col = n0 + wc * 64 + ni * 16 + lr;
          Po[orow * HDIM + col] = (bf16_t)acc[mi][ni][j];
        }
      }
  }
#undef ST_A
#undef ST_B
#undef RD_A
#undef RD_B
#undef MMQ
#undef KTILE
}

__global__ __launch_bounds__(512, 2)
void gu_gemm(const bf16_t* A0, const bf16_t* A1, const bf16_t* B0, const bf16_t* B1,
             bf16_t* O0, bf16_t* O1, bf16_t* O2, const float* bg, const float* bu,
             const int* meta, const int* tok_idx) {
  gemm8p_body<0>(A0, A1, B0, B1, O0, O1, O2, bg, bu, meta, tok_idx);
}
__global__ __launch_bounds__(512, 2)
void dn_gemm(const bf16_t* A0, const bf16_t* A1, const bf16_t* B0, const bf16_t* B1,
             bf16_t* O0, bf16_t* O1, bf16_t* O2, const float* bg, const float* bu,
             const int* meta, const int* tok_idx) {
  gemm8p_body<1>(A0, A1, B0, B1, O0, O1, O2, bg, bu, meta, tok_idx);
}

// out[t] = sh0[t]+sh1[t] + w1*rt[s1] + w2*rt[s2] + sdb
__global__ void combine_kernel(const bf16_t* __restrict__ sh0, const bf16_t* __restrict__ sh1,
                               const bf16_t* __restrict__ rt, const int* __restrict__ tk_slot,
                               const float* __restrict__ tk_w, const float* __restrict__ sdb,
                               float* __restrict__ out) {
  const int t = blockIdx.x;
  const int c = threadIdx.x * 8;
  const int s1 = tk_slot[2 * t], s2 = tk_slot[2 * t + 1];
  const float w1 = tk_w[2 * t], w2 = tk_w[2 * t + 1];
  bf16x8 a = *(const bf16x8*)(sh0 + (size_t)t * HDIM + c);
  bf16x8 b = *(const bf16x8*)(sh1 + (size_t)t * HDIM + c);
  bf16x8 r1 = *(const bf16x8*)(rt + (size_t)s1 * HDIM + c);
  bf16x8 r2 = *(const bf16x8*)(rt + (size_t)s2 * HDIM + c);
  float4 d0 = *(const float4*)(sdb + c);
  float4 d1 = *(const float4*)(sdb + c + 4);
  float o[8];
#pragma unroll
  for (int i = 0; i < 8; i++)
    o[i] = (float)a[i] + (float)b[i] + w1 * (float)r1[i] + w2 * (float)r2[i];
  o[0] += d0.x; o[1] += d0.y; o[2] += d0.z; o[3] += d0.w;
  o[4] += d1.x; o[5] += d1.y; o[6] += d1.z; o[7] += d1.w;
  float4* op = (float4*)(out + (size_t)t * HDIM + c);
  op[0] = make_float4(o[0], o[1], o[2], o[3]);
  op[1] = make_float4(o[4], o[5], o[6], o[7]);
}

extern "C" void kernel_launch(void* const* d_in, const int* in_sizes, int n_in,
                              void* d_out, int out_size, void* d_ws, size_t ws_size,
                              hipStream_t stream) {
  const float* x_f  = (const float*)d_in[0];
  const float* rw   = (const float*)d_in[1];
  const float* gate = (const float*)d_in[2];
  const float* up   = (const float*)d_in[3];
  const float* down = (const float*)d_in[4];
  const float* sgw  = (const float*)d_in[5];
  const float* sgb  = (const float*)d_in[6];
  const float* suw  = (const float*)d_in[7];
  const float* sub  = (const float*)d_in[8];
  const float* sdw  = (const float*)d_in[9];
  const float* sdb  = (const float*)d_in[10];
  float* out = (float*)d_out;

  char* ws = (char*)d_ws;
  size_t off = 0;
  auto alloc = [&](size_t bytes) {
    char* p = ws + off;
    off += (bytes + 255) & ~(size_t)255;
    return p;
  };
  bf16_t* xb    = (bf16_t*)alloc((size_t)T_TOK * HDIM * 2);
  char*   bgur  = alloc((size_t)NEXP * 2 * IDIM * HDIM * 2);            // 92.3MB
  bf16_t* BguR  = (bf16_t*)bgur;
  bf16_t* BguS  = (bf16_t*)alloc((size_t)2 * SIDIM * HDIM * 2);
  bf16_t* dT    = (bf16_t*)alloc((size_t)NEXP * HDIM * IDIM * 2);
  bf16_t* sdT   = (bf16_t*)alloc((size_t)HDIM * SIDIM * 2);
  bf16_t* hid_r = (bf16_t*)alloc((size_t)(T_TOK * 2) * IDIM * 2);
  bf16_t* hid_s = (bf16_t*)alloc((size_t)T_TOK * SIDIM * 2);
  int*    meta  = (int*)alloc(1024);
  int*    tok_idx = (int*)alloc(8192 * 4);
  int*    tk_slot = (int*)alloc(8192 * 4);
  int*    tk_i    = (int*)alloc((size_t)T_TOK * 2 * 4);
  float*  tk_w2   = (float*)alloc((size_t)T_TOK * 2 * 4);

  // down partials alias BguR (dead after gateup dispatch): 33.6+16.8+16.8 <= 92.3MB
  bf16_t* rt_p  = (bf16_t*)bgur;
  bf16_t* sh_p0 = (bf16_t*)(bgur + (size_t)8192 * HDIM * 2);
  bf16_t* sh_p1 = (bf16_t*)(bgur + (size_t)8192 * HDIM * 2 + (size_t)T_TOK * HDIM * 2);

  hipMemsetAsync(meta, 0, 64, stream);  // counts + cursor

  prep_all_kernel<<<RTR_BLKS + 21120, 256, 0, stream>>>(
      x_f, rw, xb, tk_i, tk_w2, meta,
      gate, up, sgw, suw, down, sdw, BguR, BguS, dT, sdT);

  scatter_kernel<<<T_TOK / 256, 256, 0, stream>>>(tk_i, meta, tok_idx, tk_slot);

  gu_gemm<<<GU_CAP, 512, 0, stream>>>(
      xb, nullptr, BguR, BguS, hid_r, hid_s, nullptr, sgb, sub, meta, tok_idx);
  dn_gemm<<<DN_CAP, 512, 0, stream>>>(
      hid_r, hid_s, dT, sdT, rt_p, sh_p0, sh_p1, nullptr, nullptr, meta, nullptr);
  combine_kernel<<<T_TOK, 256, 0, stream>>>(sh_p0, sh_p1, rt_p, tk_slot, tk_w2, sdb, out);
}